// Round 1
// baseline (5920.892 us; speedup 1.0000x reference)
//
#include <hip/hip_runtime.h>
#include <hip/hip_bf16.h>
#include <math.h>

#define NUSER 30000
#define NITEM 30000
#define NN    60000
#define NE    1000000
#define DIMV  64
#define XW    192     // 3 * DIM, fused modality width
#define HIDW  256
#define NB    2048
#define KNB   10

// ---------------- degree / dinv ----------------
__global__ void k_deg(const int* __restrict__ src, unsigned* __restrict__ deg) {
    int e = blockIdx.x * blockDim.x + threadIdx.x;
    if (e < NE) atomicAdd(&deg[src[e]], 1u);
}

__global__ void k_dinv(const unsigned* __restrict__ deg, float* __restrict__ dinv) {
    int i = blockIdx.x * blockDim.x + threadIdx.x;
    if (i < NN) { unsigned d = deg[i]; dinv[i] = d ? rsqrtf((float)d) : 0.f; }
}

// ---------------- GEMM1: hidden = leaky_relu(A(MxK) * W(NcxK)^T + bias) ----------------
__global__ __launch_bounds__(256)
void gemm_nt_lrelu(const float* __restrict__ A, const float* __restrict__ W,
                   const float* __restrict__ bias, float* __restrict__ C,
                   int M, int Nc, int K) {
    __shared__ float As[64][33];
    __shared__ float Bs[64][33];
    int tid = threadIdx.x;
    int tx = tid & 15, ty = tid >> 4;
    int row0 = blockIdx.x * 64, col0 = blockIdx.y * 64;
    int ty4 = ty * 4, tx4 = tx * 4;
    float acc[4][4] = {};
    for (int k0 = 0; k0 < K; k0 += 32) {
        for (int l = tid; l < 64 * 32; l += 256) {
            int r = l >> 5, kk = l & 31;
            int gk = k0 + kk;
            int gr = row0 + r;
            As[r][kk] = (gr < M && gk < K) ? A[(size_t)gr * K + gk] : 0.f;
            int gc = col0 + r;
            Bs[r][kk] = (gc < Nc && gk < K) ? W[(size_t)gc * K + gk] : 0.f;
        }
        __syncthreads();
        for (int kk = 0; kk < 32; ++kk) {
            float a0 = As[ty4 + 0][kk], a1 = As[ty4 + 1][kk];
            float a2 = As[ty4 + 2][kk], a3 = As[ty4 + 3][kk];
            float b0 = Bs[tx4 + 0][kk], b1 = Bs[tx4 + 1][kk];
            float b2 = Bs[tx4 + 2][kk], b3 = Bs[tx4 + 3][kk];
            acc[0][0] += a0 * b0; acc[0][1] += a0 * b1; acc[0][2] += a0 * b2; acc[0][3] += a0 * b3;
            acc[1][0] += a1 * b0; acc[1][1] += a1 * b1; acc[1][2] += a1 * b2; acc[1][3] += a1 * b3;
            acc[2][0] += a2 * b0; acc[2][1] += a2 * b1; acc[2][2] += a2 * b2; acc[2][3] += a2 * b3;
            acc[3][0] += a3 * b0; acc[3][1] += a3 * b1; acc[3][2] += a3 * b2; acc[3][3] += a3 * b3;
        }
        __syncthreads();
    }
    for (int i = 0; i < 4; ++i) {
        int gr = row0 + ty4 + i;
        if (gr >= M) continue;
        for (int j = 0; j < 4; ++j) {
            int gc = col0 + tx4 + j;
            float v = acc[i][j] + bias[gc];
            v = v > 0.f ? v : 0.01f * v;
            C[(size_t)gr * Nc + gc] = v;
        }
    }
}

// ---------------- GEMM2 + row l2norm, writes item rows of X ----------------
// temp = hidden(Mx256) * W2(64x256)^T + b2 ; X[NUSER+i][mslot*64 + :] = l2norm(temp_row)
__global__ __launch_bounds__(256)
void gemm2_norm(const float* __restrict__ A, const float* __restrict__ W,
                const float* __restrict__ bias, float* __restrict__ X,
                int M, int mslot) {
    __shared__ float As[64][33];
    __shared__ float Bs[64][33];
    __shared__ float Ct[64][65];
    __shared__ float scale[64];
    int tid = threadIdx.x;
    int tx = tid & 15, ty = tid >> 4;
    int row0 = blockIdx.x * 64;
    int ty4 = ty * 4, tx4 = tx * 4;
    const int K = HIDW, Nc = 64;
    float acc[4][4] = {};
    for (int k0 = 0; k0 < K; k0 += 32) {
        for (int l = tid; l < 64 * 32; l += 256) {
            int r = l >> 5, kk = l & 31;
            int gk = k0 + kk;
            int gr = row0 + r;
            As[r][kk] = (gr < M) ? A[(size_t)gr * K + gk] : 0.f;
            Bs[r][kk] = W[(size_t)r * K + gk];   // Nc==64, always in range
        }
        __syncthreads();
        for (int kk = 0; kk < 32; ++kk) {
            float a0 = As[ty4 + 0][kk], a1 = As[ty4 + 1][kk];
            float a2 = As[ty4 + 2][kk], a3 = As[ty4 + 3][kk];
            float b0 = Bs[tx4 + 0][kk], b1 = Bs[tx4 + 1][kk];
            float b2 = Bs[tx4 + 2][kk], b3 = Bs[tx4 + 3][kk];
            acc[0][0] += a0 * b0; acc[0][1] += a0 * b1; acc[0][2] += a0 * b2; acc[0][3] += a0 * b3;
            acc[1][0] += a1 * b0; acc[1][1] += a1 * b1; acc[1][2] += a1 * b2; acc[1][3] += a1 * b3;
            acc[2][0] += a2 * b0; acc[2][1] += a2 * b1; acc[2][2] += a2 * b2; acc[2][3] += a2 * b3;
            acc[3][0] += a3 * b0; acc[3][1] += a3 * b1; acc[3][2] += a3 * b2; acc[3][3] += a3 * b3;
        }
        __syncthreads();
    }
    for (int i = 0; i < 4; ++i)
        for (int j = 0; j < 4; ++j)
            Ct[ty4 + i][tx4 + j] = acc[i][j] + bias[tx4 + j];
    __syncthreads();
    if (tid < 64) {
        float s = 0.f;
        for (int c = 0; c < 64; ++c) { float v = Ct[tid][c]; s += v * v; }
        scale[tid] = 1.f / fmaxf(sqrtf(s), 1e-12f);
    }
    __syncthreads();
    for (int l = tid; l < 64 * 64; l += 256) {
        int r = l >> 6, c = l & 63;
        int gr = row0 + r;
        if (gr < M)
            X[(size_t)(NUSER + gr) * XW + mslot * DIMV + c] = Ct[r][c] * scale[r];
    }
}

// ---------------- user rows of X: l2norm(pref) per modality ----------------
__global__ void k_users_norm(const float* __restrict__ vp, const float* __restrict__ ap,
                             const float* __restrict__ tp, float* __restrict__ X) {
    int gw = (blockIdx.x * blockDim.x + threadIdx.x) >> 6;
    int lane = threadIdx.x & 63;
    if (gw >= NUSER * 3) return;
    int u = gw / 3, m = gw % 3;
    const float* p = (m == 0) ? vp : (m == 1) ? ap : tp;
    float v = p[(size_t)u * DIMV + lane];
    float s = v * v;
    for (int o = 32; o > 0; o >>= 1) s += __shfl_xor(s, o);
    float sc = 1.f / fmaxf(sqrtf(s), 1e-12f);
    X[(size_t)u * XW + m * DIMV + lane] = v * sc;
}

// ---------------- SpMM: OUT[dst] += dinv[src]*dinv[dst] * IN[src] (192-wide) --------
__global__ void k_conv(const int* __restrict__ src, const int* __restrict__ dst,
                       const float* __restrict__ dinv, const float* __restrict__ IN,
                       float* __restrict__ OUT) {
    int t = blockIdx.x * blockDim.x + threadIdx.x;   // (edge, chunk): 48 chunks of 4 floats
    if (t >= NE * 48) return;
    int e = t / 48;
    int c = (t - e * 48) * 4;
    int s = src[e], d = dst[e];
    float w = dinv[s] * dinv[d];
    float4 v = *(const float4*)(IN + (size_t)s * XW + c);
    float* o = OUT + (size_t)d * XW + c;
    atomicAdd(o + 0, w * v.x);
    atomicAdd(o + 1, w * v.y);
    atomicAdd(o + 2, w * v.z);
    atomicAdd(o + 3, w * v.w);
}

// ---------------- REP = X + H ----------------
__global__ void k_add(const float* __restrict__ X, const float* __restrict__ H,
                      float* __restrict__ REP) {
    int t = blockIdx.x * blockDim.x + threadIdx.x;
    if (t >= NN * XW / 4) return;
    float4 a = ((const float4*)X)[t];
    float4 b = ((const float4*)H)[t];
    float4 r;
    r.x = a.x + b.x; r.y = a.y + b.y; r.z = a.z + b.z; r.w = a.w + b.w;
    ((float4*)REP)[t] = r;
}

// ---------------- combine modalities: users -> UR (weighted), items -> RES (mean) ----
__global__ void k_combine(const float* __restrict__ REP, const float* __restrict__ wu,
                          float* __restrict__ UR, float* __restrict__ RES) {
    int t = blockIdx.x * blockDim.x + threadIdx.x;
    if (t >= NN * DIMV) return;
    int n = t >> 6, d = t & 63;
    const float* r = REP + (size_t)n * XW;
    float r0 = r[d], r1 = r[DIMV + d], r2 = r[2 * DIMV + d];
    if (n < NUSER) {
        float w0 = wu[n * 3 + 0], w1 = wu[n * 3 + 1], w2 = wu[n * 3 + 2];
        UR[(size_t)n * DIMV + d] = r0 * w0 + r1 * w1 + r2 * w2;
    } else {
        RES[(size_t)n * DIMV + d] = (r0 + r1 + r2) * (1.f / 3.f);
    }
}

// ---------------- user graph aggregation: RES[u] = UR[u] + sum_k w[u,k]*UR[g[u,k]] ----
__global__ void k_usergraph(const float* __restrict__ UR, const int* __restrict__ g,
                            const float* __restrict__ w, float* __restrict__ RES) {
    int t = blockIdx.x * blockDim.x + threadIdx.x;
    if (t >= NUSER * DIMV) return;
    int n = t >> 6, d = t & 63;
    float acc = UR[(size_t)n * DIMV + d];
    for (int k = 0; k < KNB; ++k) {
        int nb = g[n * KNB + k];
        acc += w[n * KNB + k] * UR[(size_t)nb * DIMV + d];
    }
    RES[(size_t)n * DIMV + d] = acc;
}

// ---------------- final scores ----------------
__global__ void k_scores(const float* __restrict__ RES, const int* __restrict__ un,
                         const int* __restrict__ pn, const int* __restrict__ nn,
                         float* __restrict__ out) {
    int gw = (blockIdx.x * blockDim.x + threadIdx.x) >> 6;
    int lane = threadIdx.x & 63;
    if (gw >= NB) return;
    int u = un[gw], p = pn[gw], ng = nn[gw];
    float uv = RES[(size_t)u * DIMV + lane];
    float ps = uv * RES[(size_t)p * DIMV + lane];
    float ns = uv * RES[(size_t)ng * DIMV + lane];
    for (int o = 32; o > 0; o >>= 1) {
        ps += __shfl_xor(ps, o);
        ns += __shfl_xor(ns, o);
    }
    if (lane == 0) { out[gw] = ps; out[NB + gw] = ns; }
}

extern "C" void kernel_launch(void* const* d_in, const int* in_sizes, int n_in,
                              void* d_out, int out_size, void* d_ws, size_t ws_size,
                              hipStream_t stream) {
    const int*   un    = (const int*)d_in[0];
    const int*   pn    = (const int*)d_in[1];
    const int*   ngn   = (const int*)d_in[2];
    const int*   ug    = (const int*)d_in[3];
    const int*   eidx  = (const int*)d_in[4];
    const float* uwm   = (const float*)d_in[5];
    const float* feats[3] = { (const float*)d_in[6], (const float*)d_in[7], (const float*)d_in[8] };
    const int    featK[3] = { 1024, 128, 100 };
    const float* prefs[3] = { (const float*)d_in[9], (const float*)d_in[10], (const float*)d_in[11] };
    const float* W1[3] = { (const float*)d_in[12], (const float*)d_in[16], (const float*)d_in[20] };
    const float* b1[3] = { (const float*)d_in[13], (const float*)d_in[17], (const float*)d_in[21] };
    const float* W2[3] = { (const float*)d_in[14], (const float*)d_in[18], (const float*)d_in[22] };
    const float* b2[3] = { (const float*)d_in[15], (const float*)d_in[19], (const float*)d_in[23] };
    const float* wu    = (const float*)d_in[24];
    float* out = (float*)d_out;

    const int* esrc = eidx;            // edge_index[0]
    const int* edst = eidx + NE;       // edge_index[1]

    // workspace layout (all 256B aligned)
    char* ws = (char*)d_ws;
    size_t off = 0;
    auto alloc = [&](size_t bytes) { void* p = ws + off; off = (off + bytes + 255) & ~(size_t)255; return p; };
    unsigned* deg  = (unsigned*)alloc(NN * sizeof(unsigned));
    float*    dinv = (float*)alloc(NN * sizeof(float));
    float*    X    = (float*)alloc((size_t)NN * XW * sizeof(float));
    float*    H    = (float*)alloc((size_t)NN * XW * sizeof(float));  // first 30000*256 doubles as GEMM hidden
    float*    REP  = (float*)alloc((size_t)NN * XW * sizeof(float));
    float*    UR   = (float*)alloc((size_t)NUSER * DIMV * sizeof(float));
    float*    RES  = (float*)alloc((size_t)NN * DIMV * sizeof(float));
    float*    hidden = H;  // alias: 30000*256 floats < NN*XW floats

    // 1. degrees
    hipMemsetAsync(deg, 0, NN * sizeof(unsigned), stream);
    k_deg<<<(NE + 255) / 256, 256, 0, stream>>>(esrc, deg);
    k_dinv<<<(NN + 255) / 256, 256, 0, stream>>>(deg, dinv);

    // 2. per-modality MLP -> item rows of X (l2-normalized)
    for (int m = 0; m < 3; ++m) {
        dim3 g1((NITEM + 63) / 64, HIDW / 64);
        gemm_nt_lrelu<<<g1, 256, 0, stream>>>(feats[m], W1[m], b1[m], hidden,
                                              NITEM, HIDW, featK[m]);
        gemm2_norm<<<(NITEM + 63) / 64, 256, 0, stream>>>(hidden, W2[m], b2[m], X,
                                                          NITEM, m);
    }
    // user rows of X
    k_users_norm<<<(NUSER * 3 * 64 + 255) / 256, 256, 0, stream>>>(prefs[0], prefs[1], prefs[2], X);

    // 3. conv1: H = A * X
    hipMemsetAsync(H, 0, (size_t)NN * XW * sizeof(float), stream);
    k_conv<<<(NE * 48 + 255) / 256, 256, 0, stream>>>(esrc, edst, dinv, X, H);

    // 4. REP = X + H ; conv2 accumulates A*H into REP
    k_add<<<(NN * XW / 4 + 255) / 256, 256, 0, stream>>>(X, H, REP);
    k_conv<<<(NE * 48 + 255) / 256, 256, 0, stream>>>(esrc, edst, dinv, H, REP);

    // 5. combine modalities
    k_combine<<<(NN * DIMV + 255) / 256, 256, 0, stream>>>(REP, wu, UR, RES);

    // 6. user-graph aggregation
    k_usergraph<<<(NUSER * DIMV + 255) / 256, 256, 0, stream>>>(UR, ug, uwm, RES);

    // 7. scores
    k_scores<<<(NB * 64 + 255) / 256, 256, 0, stream>>>(RES, un, pn, ngn, out);
}

// Round 2
// 1181.997 us; speedup vs baseline: 5.0092x; 5.0092x over previous
//
#include <hip/hip_runtime.h>
#include <hip/hip_bf16.h>
#include <math.h>

#define NUSER 30000
#define NITEM 30000
#define NN    60000
#define NE    1000000
#define DIMV  64
#define XW    192     // 3 * DIM, fused modality width
#define HIDW  256
#define NB    2048
#define KNB   10

// ---------------- degree ----------------
__global__ void k_deg(const int* __restrict__ src, unsigned* __restrict__ deg) {
    int e = blockIdx.x * blockDim.x + threadIdx.x;
    if (e < NE) atomicAdd(&deg[src[e]], 1u);
}

__global__ void k_dinv(const unsigned* __restrict__ deg, float* __restrict__ dinv) {
    int i = blockIdx.x * blockDim.x + threadIdx.x;
    if (i < NN) { unsigned d = deg[i]; dinv[i] = d ? rsqrtf((float)d) : 0.f; }
}

// ---------------- exclusive scan of deg -> rowptr (single block) ----------------
__global__ __launch_bounds__(1024)
void k_scan(const unsigned* __restrict__ deg, int* __restrict__ rowptr) {
    __shared__ int sums[1024];
    const int T = 1024, CH = (NN + T - 1) / T;   // 59
    int t = threadIdx.x;
    int lo = t * CH, hi = min(lo + CH, NN);
    int s = 0;
    for (int i = lo; i < hi; ++i) s += (int)deg[i];
    sums[t] = s;
    __syncthreads();
    for (int o = 1; o < T; o <<= 1) {
        int v = (t >= o) ? sums[t - o] : 0;
        __syncthreads();
        sums[t] += v;
        __syncthreads();
    }
    int run = sums[t] - s;   // exclusive prefix of this chunk
    for (int i = lo; i < hi; ++i) { rowptr[i] = run; run += (int)deg[i]; }
    if (t == T - 1) rowptr[NN] = run;
}

// ---------------- fill CSR (keyed by dst): csr[j] = {src, weight} ----------------
__global__ void k_fill(const int* __restrict__ src, const int* __restrict__ dst,
                       const float* __restrict__ dinv, const int* __restrict__ rowptr,
                       unsigned* __restrict__ cursor, int2* __restrict__ csr) {
    int e = blockIdx.x * blockDim.x + threadIdx.x;
    if (e >= NE) return;
    int s = src[e], d = dst[e];
    int pos = (int)atomicAdd(&cursor[d], 1u);
    int idx = rowptr[d] + pos;
    int2 ew;
    ew.x = s;
    ew.y = __float_as_int(dinv[s] * dinv[d]);
    csr[idx] = ew;
}

// ---------------- gather SpMM: OUT[n] = sum_j w_j * IN[s_j]  (+ optional X[n]+H[n]) ----
template<bool FUSE>
__global__ __launch_bounds__(256)
void k_spmm(const int* __restrict__ rowptr, const int2* __restrict__ csr,
            const float* __restrict__ IN, float* __restrict__ OUT,
            const float* __restrict__ ADD) {   // FUSE: OUT[n] = ADD[n] + IN[n] + A*IN
    int n = blockIdx.x * 4 + (threadIdx.x >> 6);
    int lane = threadIdx.x & 63;
    if (n >= NN) return;
    int lo = rowptr[n], hi = rowptr[n + 1];
    float a0 = 0.f, a1 = 0.f, a2 = 0.f;
    for (int j = lo; j < hi; ++j) {
        int2 ew = csr[j];                       // uniform across wave -> broadcast
        float w = __int_as_float(ew.y);
        const float* p = IN + (size_t)ew.x * XW;
        a0 += w * p[lane];
        a1 += w * p[64 + lane];
        a2 += w * p[128 + lane];
    }
    size_t o = (size_t)n * XW;
    if (FUSE) {
        a0 += ADD[o + lane]        + IN[o + lane];
        a1 += ADD[o + 64 + lane]   + IN[o + 64 + lane];
        a2 += ADD[o + 128 + lane]  + IN[o + 128 + lane];
    }
    OUT[o + lane] = a0;
    OUT[o + 64 + lane] = a1;
    OUT[o + 128 + lane] = a2;
}

// ---------------- GEMM1: hidden = leaky_relu(A(MxK) * W(NcxK)^T + bias) ----------------
__global__ __launch_bounds__(256)
void gemm_nt_lrelu(const float* __restrict__ A, const float* __restrict__ W,
                   const float* __restrict__ bias, float* __restrict__ C,
                   int M, int Nc, int K) {
    __shared__ float As[64][33];
    __shared__ float Bs[64][33];
    int tid = threadIdx.x;
    int tx = tid & 15, ty = tid >> 4;
    int row0 = blockIdx.x * 64, col0 = blockIdx.y * 64;
    int ty4 = ty * 4, tx4 = tx * 4;
    float acc[4][4] = {};
    for (int k0 = 0; k0 < K; k0 += 32) {
        for (int l = tid; l < 64 * 32; l += 256) {
            int r = l >> 5, kk = l & 31;
            int gk = k0 + kk;
            int gr = row0 + r;
            As[r][kk] = (gr < M && gk < K) ? A[(size_t)gr * K + gk] : 0.f;
            int gc = col0 + r;
            Bs[r][kk] = (gc < Nc && gk < K) ? W[(size_t)gc * K + gk] : 0.f;
        }
        __syncthreads();
        for (int kk = 0; kk < 32; ++kk) {
            float a0 = As[ty4 + 0][kk], a1 = As[ty4 + 1][kk];
            float a2 = As[ty4 + 2][kk], a3 = As[ty4 + 3][kk];
            float b0 = Bs[tx4 + 0][kk], b1 = Bs[tx4 + 1][kk];
            float b2 = Bs[tx4 + 2][kk], b3 = Bs[tx4 + 3][kk];
            acc[0][0] += a0 * b0; acc[0][1] += a0 * b1; acc[0][2] += a0 * b2; acc[0][3] += a0 * b3;
            acc[1][0] += a1 * b0; acc[1][1] += a1 * b1; acc[1][2] += a1 * b2; acc[1][3] += a1 * b3;
            acc[2][0] += a2 * b0; acc[2][1] += a2 * b1; acc[2][2] += a2 * b2; acc[2][3] += a2 * b3;
            acc[3][0] += a3 * b0; acc[3][1] += a3 * b1; acc[3][2] += a3 * b2; acc[3][3] += a3 * b3;
        }
        __syncthreads();
    }
    for (int i = 0; i < 4; ++i) {
        int gr = row0 + ty4 + i;
        if (gr >= M) continue;
        for (int j = 0; j < 4; ++j) {
            int gc = col0 + tx4 + j;
            float v = acc[i][j] + bias[gc];
            v = v > 0.f ? v : 0.01f * v;
            C[(size_t)gr * Nc + gc] = v;
        }
    }
}

// ---------------- GEMM2 + row l2norm, writes item rows of X ----------------
__global__ __launch_bounds__(256)
void gemm2_norm(const float* __restrict__ A, const float* __restrict__ W,
                const float* __restrict__ bias, float* __restrict__ X,
                int M, int mslot) {
    __shared__ float As[64][33];
    __shared__ float Bs[64][33];
    __shared__ float Ct[64][65];
    __shared__ float scale[64];
    int tid = threadIdx.x;
    int tx = tid & 15, ty = tid >> 4;
    int row0 = blockIdx.x * 64;
    int ty4 = ty * 4, tx4 = tx * 4;
    const int K = HIDW;
    float acc[4][4] = {};
    for (int k0 = 0; k0 < K; k0 += 32) {
        for (int l = tid; l < 64 * 32; l += 256) {
            int r = l >> 5, kk = l & 31;
            int gk = k0 + kk;
            int gr = row0 + r;
            As[r][kk] = (gr < M) ? A[(size_t)gr * K + gk] : 0.f;
            Bs[r][kk] = W[(size_t)r * K + gk];
        }
        __syncthreads();
        for (int kk = 0; kk < 32; ++kk) {
            float a0 = As[ty4 + 0][kk], a1 = As[ty4 + 1][kk];
            float a2 = As[ty4 + 2][kk], a3 = As[ty4 + 3][kk];
            float b0 = Bs[tx4 + 0][kk], b1 = Bs[tx4 + 1][kk];
            float b2 = Bs[tx4 + 2][kk], b3 = Bs[tx4 + 3][kk];
            acc[0][0] += a0 * b0; acc[0][1] += a0 * b1; acc[0][2] += a0 * b2; acc[0][3] += a0 * b3;
            acc[1][0] += a1 * b0; acc[1][1] += a1 * b1; acc[1][2] += a1 * b2; acc[1][3] += a1 * b3;
            acc[2][0] += a2 * b0; acc[2][1] += a2 * b1; acc[2][2] += a2 * b2; acc[2][3] += a2 * b3;
            acc[3][0] += a3 * b0; acc[3][1] += a3 * b1; acc[3][2] += a3 * b2; acc[3][3] += a3 * b3;
        }
        __syncthreads();
    }
    for (int i = 0; i < 4; ++i)
        for (int j = 0; j < 4; ++j)
            Ct[ty4 + i][tx4 + j] = acc[i][j] + bias[tx4 + j];
    __syncthreads();
    if (tid < 64) {
        float s = 0.f;
        for (int c = 0; c < 64; ++c) { float v = Ct[tid][c]; s += v * v; }
        scale[tid] = 1.f / fmaxf(sqrtf(s), 1e-12f);
    }
    __syncthreads();
    for (int l = tid; l < 64 * 64; l += 256) {
        int r = l >> 6, c = l & 63;
        int gr = row0 + r;
        if (gr < M)
            X[(size_t)(NUSER + gr) * XW + mslot * DIMV + c] = Ct[r][c] * scale[r];
    }
}

// ---------------- user rows of X: l2norm(pref) per modality ----------------
__global__ void k_users_norm(const float* __restrict__ vp, const float* __restrict__ ap,
                             const float* __restrict__ tp, float* __restrict__ X) {
    int gw = (blockIdx.x * blockDim.x + threadIdx.x) >> 6;
    int lane = threadIdx.x & 63;
    if (gw >= NUSER * 3) return;
    int u = gw / 3, m = gw % 3;
    const float* p = (m == 0) ? vp : (m == 1) ? ap : tp;
    float v = p[(size_t)u * DIMV + lane];
    float s = v * v;
    for (int o = 32; o > 0; o >>= 1) s += __shfl_xor(s, o);
    float sc = 1.f / fmaxf(sqrtf(s), 1e-12f);
    X[(size_t)u * XW + m * DIMV + lane] = v * sc;
}

// ---------------- combine modalities: users -> UR (weighted), items -> RES (mean) ----
__global__ void k_combine(const float* __restrict__ REP, const float* __restrict__ wu,
                          float* __restrict__ UR, float* __restrict__ RES) {
    int t = blockIdx.x * blockDim.x + threadIdx.x;
    if (t >= NN * DIMV) return;
    int n = t >> 6, d = t & 63;
    const float* r = REP + (size_t)n * XW;
    float r0 = r[d], r1 = r[DIMV + d], r2 = r[2 * DIMV + d];
    if (n < NUSER) {
        float w0 = wu[n * 3 + 0], w1 = wu[n * 3 + 1], w2 = wu[n * 3 + 2];
        UR[(size_t)n * DIMV + d] = r0 * w0 + r1 * w1 + r2 * w2;
    } else {
        RES[(size_t)n * DIMV + d] = (r0 + r1 + r2) * (1.f / 3.f);
    }
}

// ---------------- user graph aggregation ----------------
__global__ void k_usergraph(const float* __restrict__ UR, const int* __restrict__ g,
                            const float* __restrict__ w, float* __restrict__ RES) {
    int t = blockIdx.x * blockDim.x + threadIdx.x;
    if (t >= NUSER * DIMV) return;
    int n = t >> 6, d = t & 63;
    float acc = UR[(size_t)n * DIMV + d];
    for (int k = 0; k < KNB; ++k) {
        int nb = g[n * KNB + k];
        acc += w[n * KNB + k] * UR[(size_t)nb * DIMV + d];
    }
    RES[(size_t)n * DIMV + d] = acc;
}

// ---------------- final scores ----------------
__global__ void k_scores(const float* __restrict__ RES, const int* __restrict__ un,
                         const int* __restrict__ pn, const int* __restrict__ nn,
                         float* __restrict__ out) {
    int gw = (blockIdx.x * blockDim.x + threadIdx.x) >> 6;
    int lane = threadIdx.x & 63;
    if (gw >= NB) return;
    int u = un[gw], p = pn[gw], ng = nn[gw];
    float uv = RES[(size_t)u * DIMV + lane];
    float ps = uv * RES[(size_t)p * DIMV + lane];
    float ns = uv * RES[(size_t)ng * DIMV + lane];
    for (int o = 32; o > 0; o >>= 1) {
        ps += __shfl_xor(ps, o);
        ns += __shfl_xor(ns, o);
    }
    if (lane == 0) { out[gw] = ps; out[NB + gw] = ns; }
}

extern "C" void kernel_launch(void* const* d_in, const int* in_sizes, int n_in,
                              void* d_out, int out_size, void* d_ws, size_t ws_size,
                              hipStream_t stream) {
    const int*   un    = (const int*)d_in[0];
    const int*   pn    = (const int*)d_in[1];
    const int*   ngn   = (const int*)d_in[2];
    const int*   ug    = (const int*)d_in[3];
    const int*   eidx  = (const int*)d_in[4];
    const float* uwm   = (const float*)d_in[5];
    const float* feats[3] = { (const float*)d_in[6], (const float*)d_in[7], (const float*)d_in[8] };
    const int    featK[3] = { 1024, 128, 100 };
    const float* prefs[3] = { (const float*)d_in[9], (const float*)d_in[10], (const float*)d_in[11] };
    const float* W1[3] = { (const float*)d_in[12], (const float*)d_in[16], (const float*)d_in[20] };
    const float* b1[3] = { (const float*)d_in[13], (const float*)d_in[17], (const float*)d_in[21] };
    const float* W2[3] = { (const float*)d_in[14], (const float*)d_in[18], (const float*)d_in[22] };
    const float* b2[3] = { (const float*)d_in[15], (const float*)d_in[19], (const float*)d_in[23] };
    const float* wu    = (const float*)d_in[24];
    float* out = (float*)d_out;

    const int* esrc = eidx;            // edge_index[0]
    const int* edst = eidx + NE;       // edge_index[1]

    // workspace layout
    char* ws = (char*)d_ws;
    size_t off = 0;
    auto alloc = [&](size_t bytes) { void* p = ws + off; off = (off + bytes + 255) & ~(size_t)255; return p; };
    unsigned* deg    = (unsigned*)alloc(NN * sizeof(unsigned));   // reused as CSR cursor
    float*    dinv   = (float*)alloc(NN * sizeof(float));
    int*      rowptr = (int*)alloc((NN + 1) * sizeof(int));
    int2*     csr    = (int2*)alloc((size_t)NE * sizeof(int2));
    float*    X      = (float*)alloc((size_t)NN * XW * sizeof(float));  // also holds REP after conv2
    float*    H      = (float*)alloc((size_t)NN * XW * sizeof(float));  // first 30000*256 doubles as GEMM hidden
    float*    UR     = (float*)alloc((size_t)NUSER * DIMV * sizeof(float));
    float*    RES    = (float*)alloc((size_t)NN * DIMV * sizeof(float));
    float*    hidden = H;

    // 1. degrees + CSR build
    hipMemsetAsync(deg, 0, NN * sizeof(unsigned), stream);
    k_deg<<<(NE + 255) / 256, 256, 0, stream>>>(esrc, deg);
    k_dinv<<<(NN + 255) / 256, 256, 0, stream>>>(deg, dinv);
    k_scan<<<1, 1024, 0, stream>>>(deg, rowptr);
    hipMemsetAsync(deg, 0, NN * sizeof(unsigned), stream);   // deg becomes cursor
    k_fill<<<(NE + 255) / 256, 256, 0, stream>>>(esrc, edst, dinv, rowptr, deg, csr);

    // 2. per-modality MLP -> item rows of X (l2-normalized)
    for (int m = 0; m < 3; ++m) {
        dim3 g1((NITEM + 63) / 64, HIDW / 64);
        gemm_nt_lrelu<<<g1, 256, 0, stream>>>(feats[m], W1[m], b1[m], hidden,
                                              NITEM, HIDW, featK[m]);
        gemm2_norm<<<(NITEM + 63) / 64, 256, 0, stream>>>(hidden, W2[m], b2[m], X,
                                                          NITEM, m);
    }
    k_users_norm<<<(NUSER * 3 * 64 + 255) / 256, 256, 0, stream>>>(prefs[0], prefs[1], prefs[2], X);

    // 3. conv1: H = A * X  (gather, no atomics)
    k_spmm<false><<<(NN + 3) / 4, 256, 0, stream>>>(rowptr, csr, X, H, nullptr);

    // 4. conv2 fused: X(=REP) = X + H + A * H   (in-place over X; gathers touch only H)
    k_spmm<true><<<(NN + 3) / 4, 256, 0, stream>>>(rowptr, csr, H, X, X);

    // 5. combine modalities
    k_combine<<<(NN * DIMV + 255) / 256, 256, 0, stream>>>(X, wu, UR, RES);

    // 6. user-graph aggregation
    k_usergraph<<<(NUSER * DIMV + 255) / 256, 256, 0, stream>>>(UR, ug, uwm, RES);

    // 7. scores
    k_scores<<<(NB * 64 + 255) / 256, 256, 0, stream>>>(RES, un, pn, ngn, out);
}

// Round 3
// 681.725 us; speedup vs baseline: 8.6852x; 1.7338x over previous
//
#include <hip/hip_runtime.h>
#include <hip/hip_bf16.h>
#include <math.h>

#define NUSER 30000
#define NITEM 30000
#define NN    60000
#define NE    1000000
#define DIMV  64
#define XW    192     // 3 * DIM, fused modality width
#define HIDW  256
#define NB    2048
#define KNB   10

typedef __attribute__((ext_vector_type(8))) short bf16x8;
typedef __attribute__((ext_vector_type(4))) float f32x4;

__device__ inline short f2bf(float f) {
    union { float f; unsigned u; } v; v.f = f;
    unsigned r = v.u + 0x7fff + ((v.u >> 16) & 1);   // RNE
    return (short)(r >> 16);
}

// ---------------- degree ----------------
__global__ void k_deg(const int* __restrict__ src, unsigned* __restrict__ deg) {
    int e = blockIdx.x * blockDim.x + threadIdx.x;
    if (e < NE) atomicAdd(&deg[src[e]], 1u);
}

__global__ void k_dinv(const unsigned* __restrict__ deg, float* __restrict__ dinv) {
    int i = blockIdx.x * blockDim.x + threadIdx.x;
    if (i < NN) { unsigned d = deg[i]; dinv[i] = d ? rsqrtf((float)d) : 0.f; }
}

// ---------------- exclusive scan of deg -> rowptr (single block) ----------------
__global__ __launch_bounds__(1024)
void k_scan(const unsigned* __restrict__ deg, int* __restrict__ rowptr) {
    __shared__ int sums[1024];
    const int T = 1024, CH = (NN + T - 1) / T;
    int t = threadIdx.x;
    int lo = t * CH, hi = min(lo + CH, NN);
    int s = 0;
    for (int i = lo; i < hi; ++i) s += (int)deg[i];
    sums[t] = s;
    __syncthreads();
    for (int o = 1; o < T; o <<= 1) {
        int v = (t >= o) ? sums[t - o] : 0;
        __syncthreads();
        sums[t] += v;
        __syncthreads();
    }
    int run = sums[t] - s;
    for (int i = lo; i < hi; ++i) { rowptr[i] = run; run += (int)deg[i]; }
    if (t == T - 1) rowptr[NN] = run;
}

// ---------------- fill CSR (keyed by dst) ----------------
__global__ void k_fill(const int* __restrict__ src, const int* __restrict__ dst,
                       const float* __restrict__ dinv, const int* __restrict__ rowptr,
                       unsigned* __restrict__ cursor, int2* __restrict__ csr) {
    int e = blockIdx.x * blockDim.x + threadIdx.x;
    if (e >= NE) return;
    int s = src[e], d = dst[e];
    int pos = (int)atomicAdd(&cursor[d], 1u);
    int idx = rowptr[d] + pos;
    int2 ew;
    ew.x = s;
    ew.y = __float_as_int(dinv[s] * dinv[d]);
    csr[idx] = ew;
}

// ---------------- gather SpMM ----------------
template<bool FUSE>
__global__ __launch_bounds__(256)
void k_spmm(const int* __restrict__ rowptr, const int2* __restrict__ csr,
            const float* __restrict__ IN, float* __restrict__ OUT,
            const float* __restrict__ ADD) {
    int n = blockIdx.x * 4 + (threadIdx.x >> 6);
    int lane = threadIdx.x & 63;
    if (n >= NN) return;
    int lo = rowptr[n], hi = rowptr[n + 1];
    float a0 = 0.f, a1 = 0.f, a2 = 0.f;
    for (int j = lo; j < hi; ++j) {
        int2 ew = csr[j];
        float w = __int_as_float(ew.y);
        const float* p = IN + (size_t)ew.x * XW;
        a0 += w * p[lane];
        a1 += w * p[64 + lane];
        a2 += w * p[128 + lane];
    }
    size_t o = (size_t)n * XW;
    if (FUSE) {
        a0 += ADD[o + lane]        + IN[o + lane];
        a1 += ADD[o + 64 + lane]   + IN[o + 64 + lane];
        a2 += ADD[o + 128 + lane]  + IN[o + 128 + lane];
    }
    OUT[o + lane] = a0;
    OUT[o + 64 + lane] = a1;
    OUT[o + 128 + lane] = a2;
}

// ---------------- LDS staging with XOR swizzle (row stride 64 bf16 = 128B) ----------
// CONV: src fp32 -> bf16; else src already bf16 (ushort)
template<bool CONV>
__device__ inline void stage_tile(const void* src, int rows_total, int srcld,
                                  int row0, int k0, int K, short* lds, int tile_rows) {
    int nch = tile_rows * 8;                 // 16B chunks (8 bf16) per row: 8
    for (int l = threadIdx.x; l < nch; l += 256) {
        int r = l >> 3, c8 = l & 7;
        int grow = row0 + r, gk = k0 + c8 * 8;
        bf16x8 out;
        if (grow < rows_total) {
            if (CONV) {
                const float* s = (const float*)src + (size_t)grow * srcld + gk;
                if (gk + 8 <= K) {
                    float4 f0 = *(const float4*)s;
                    float4 f1 = *(const float4*)(s + 4);
                    out[0] = f2bf(f0.x); out[1] = f2bf(f0.y);
                    out[2] = f2bf(f0.z); out[3] = f2bf(f0.w);
                    out[4] = f2bf(f1.x); out[5] = f2bf(f1.y);
                    out[6] = f2bf(f1.z); out[7] = f2bf(f1.w);
                } else {
                    #pragma unroll
                    for (int j = 0; j < 8; ++j)
                        out[j] = (gk + j < K) ? f2bf(s[j]) : (short)0;
                }
            } else {
                const short* s = (const short*)src + (size_t)grow * srcld + gk;
                out = *(const bf16x8*)s;
            }
        } else {
            out = (bf16x8)0;
        }
        int off = (r * 128 + c8 * 16) ^ ((r & 7) << 4);
        *(bf16x8*)((char*)lds + off) = out;
    }
}

__device__ inline bf16x8 ldfrag(const short* lds, int row, int kbyte) {
    int off = (row * 128 + kbyte) ^ ((row & 7) << 4);
    return *(const bf16x8*)((const char*)lds + off);
}

// ---------------- GEMM1 (MFMA): hidden_bf16 = lrelu(A(MxK)f32 * W(256xK)^T f32 + b) ----
__global__ __launch_bounds__(256)
void gemm1_mfma(const float* __restrict__ A, const float* __restrict__ W,
                const float* __restrict__ bias, short* __restrict__ C,
                int M, int K) {
    __shared__ __align__(16) short smemA[128 * 64];
    __shared__ __align__(16) short smemB[256 * 64];
    int lane = threadIdx.x & 63, wave = threadIdx.x >> 6;
    int wr = wave >> 1, wc = wave & 1;       // 2x2 waves: 64 rows x 128 cols each
    int lane15 = lane & 15, lhi = lane >> 4;
    int row0 = blockIdx.x * 128;
    f32x4 acc[4][8] = {};
    int nk = (K + 63) / 64;
    for (int t = 0; t < nk; ++t) {
        int k0 = t * 64;
        stage_tile<true>(A, M, K, row0, k0, K, smemA, 128);
        stage_tile<true>(W, 256, K, 0, k0, K, smemB, 256);
        __syncthreads();
        #pragma unroll
        for (int ks = 0; ks < 2; ++ks) {
            int kbyte = ks * 64 + lhi * 16;
            bf16x8 a[4], b[8];
            #pragma unroll
            for (int m = 0; m < 4; ++m) a[m] = ldfrag(smemA, wr * 64 + m * 16 + lane15, kbyte);
            #pragma unroll
            for (int n = 0; n < 8; ++n) b[n] = ldfrag(smemB, wc * 128 + n * 16 + lane15, kbyte);
            #pragma unroll
            for (int m = 0; m < 4; ++m)
                #pragma unroll
                for (int n = 0; n < 8; ++n)
                    acc[m][n] = __builtin_amdgcn_mfma_f32_16x16x32_bf16(a[m], b[n], acc[m][n], 0, 0, 0);
        }
        __syncthreads();
    }
    #pragma unroll
    for (int m = 0; m < 4; ++m) {
        int grow_base = row0 + wr * 64 + m * 16 + lhi * 4;
        #pragma unroll
        for (int n = 0; n < 8; ++n) {
            int gcol = wc * 128 + n * 16 + lane15;
            float bv = bias[gcol];
            #pragma unroll
            for (int r = 0; r < 4; ++r) {
                int grow = grow_base + r;
                if (grow < M) {
                    float v = acc[m][n][r] + bv;
                    v = v > 0.f ? v : 0.01f * v;
                    C[(size_t)grow * HIDW + gcol] = f2bf(v);
                }
            }
        }
    }
}

// ---------------- GEMM2 (MFMA) + row l2norm -> item rows of X ----------------
// temp = hidden(Mx256)bf16 * W2(64x256)^T f32 + b2 ; X[NUSER+row][mslot*64+:] = l2norm(row)
__global__ __launch_bounds__(256)
void gemm2_mfma(const short* __restrict__ A, const float* __restrict__ W,
                const float* __restrict__ bias, float* __restrict__ X,
                int M, int mslot) {
    __shared__ __align__(16) short smemA[128 * 64];
    __shared__ __align__(16) short smemB[64 * 64];
    int lane = threadIdx.x & 63, wave = threadIdx.x >> 6;
    int lane15 = lane & 15, lhi = lane >> 4;
    int row0 = blockIdx.x * 128;
    const int K = HIDW;
    f32x4 acc[2][4] = {};
    for (int t = 0; t < K / 64; ++t) {
        int k0 = t * 64;
        stage_tile<false>(A, M, K, row0, k0, K, smemA, 128);
        stage_tile<true>(W, 64, K, 0, k0, K, smemB, 64);
        __syncthreads();
        #pragma unroll
        for (int ks = 0; ks < 2; ++ks) {
            int kbyte = ks * 64 + lhi * 16;
            bf16x8 a[2], b[4];
            #pragma unroll
            for (int m = 0; m < 2; ++m) a[m] = ldfrag(smemA, wave * 32 + m * 16 + lane15, kbyte);
            #pragma unroll
            for (int n = 0; n < 4; ++n) b[n] = ldfrag(smemB, n * 16 + lane15, kbyte);
            #pragma unroll
            for (int m = 0; m < 2; ++m)
                #pragma unroll
                for (int n = 0; n < 4; ++n)
                    acc[m][n] = __builtin_amdgcn_mfma_f32_16x16x32_bf16(a[m], b[n], acc[m][n], 0, 0, 0);
        }
        __syncthreads();
    }
    // epilogue: bias, row l2norm, write fp32 X slots
    #pragma unroll
    for (int m = 0; m < 2; ++m) {
        float v[4][4];
        float sumsq[4] = {};
        #pragma unroll
        for (int n = 0; n < 4; ++n) {
            float bv = bias[n * 16 + lane15];
            #pragma unroll
            for (int r = 0; r < 4; ++r) {
                float x = acc[m][n][r] + bv;
                v[n][r] = x;
                sumsq[r] += x * x;
            }
        }
        #pragma unroll
        for (int r = 0; r < 4; ++r) {
            float s = sumsq[r];
            s += __shfl_xor(s, 1); s += __shfl_xor(s, 2);
            s += __shfl_xor(s, 4); s += __shfl_xor(s, 8);
            sumsq[r] = 1.f / fmaxf(sqrtf(s), 1e-12f);
        }
        int grow_base = row0 + wave * 32 + m * 16 + lhi * 4;
        #pragma unroll
        for (int r = 0; r < 4; ++r) {
            int grow = grow_base + r;
            if (grow < M) {
                float sc = sumsq[r];
                #pragma unroll
                for (int n = 0; n < 4; ++n)
                    X[(size_t)(NUSER + grow) * XW + mslot * DIMV + n * 16 + lane15] = v[n][r] * sc;
            }
        }
    }
}

// ---------------- user rows of X: l2norm(pref) per modality ----------------
__global__ void k_users_norm(const float* __restrict__ vp, const float* __restrict__ ap,
                             const float* __restrict__ tp, float* __restrict__ X) {
    int gw = (blockIdx.x * blockDim.x + threadIdx.x) >> 6;
    int lane = threadIdx.x & 63;
    if (gw >= NUSER * 3) return;
    int u = gw / 3, m = gw % 3;
    const float* p = (m == 0) ? vp : (m == 1) ? ap : tp;
    float v = p[(size_t)u * DIMV + lane];
    float s = v * v;
    for (int o = 32; o > 0; o >>= 1) s += __shfl_xor(s, o);
    float sc = 1.f / fmaxf(sqrtf(s), 1e-12f);
    X[(size_t)u * XW + m * DIMV + lane] = v * sc;
}

// ---------------- combine modalities ----------------
__global__ void k_combine(const float* __restrict__ REP, const float* __restrict__ wu,
                          float* __restrict__ UR, float* __restrict__ RES) {
    int t = blockIdx.x * blockDim.x + threadIdx.x;
    if (t >= NN * DIMV) return;
    int n = t >> 6, d = t & 63;
    const float* r = REP + (size_t)n * XW;
    float r0 = r[d], r1 = r[DIMV + d], r2 = r[2 * DIMV + d];
    if (n < NUSER) {
        float w0 = wu[n * 3 + 0], w1 = wu[n * 3 + 1], w2 = wu[n * 3 + 2];
        UR[(size_t)n * DIMV + d] = r0 * w0 + r1 * w1 + r2 * w2;
    } else {
        RES[(size_t)n * DIMV + d] = (r0 + r1 + r2) * (1.f / 3.f);
    }
}

// ---------------- user graph aggregation ----------------
__global__ void k_usergraph(const float* __restrict__ UR, const int* __restrict__ g,
                            const float* __restrict__ w, float* __restrict__ RES) {
    int t = blockIdx.x * blockDim.x + threadIdx.x;
    if (t >= NUSER * DIMV) return;
    int n = t >> 6, d = t & 63;
    float acc = UR[(size_t)n * DIMV + d];
    for (int k = 0; k < KNB; ++k) {
        int nb = g[n * KNB + k];
        acc += w[n * KNB + k] * UR[(size_t)nb * DIMV + d];
    }
    RES[(size_t)n * DIMV + d] = acc;
}

// ---------------- final scores ----------------
__global__ void k_scores(const float* __restrict__ RES, const int* __restrict__ un,
                         const int* __restrict__ pn, const int* __restrict__ nn,
                         float* __restrict__ out) {
    int gw = (blockIdx.x * blockDim.x + threadIdx.x) >> 6;
    int lane = threadIdx.x & 63;
    if (gw >= NB) return;
    int u = un[gw], p = pn[gw], ng = nn[gw];
    float uv = RES[(size_t)u * DIMV + lane];
    float ps = uv * RES[(size_t)p * DIMV + lane];
    float ns = uv * RES[(size_t)ng * DIMV + lane];
    for (int o = 32; o > 0; o >>= 1) {
        ps += __shfl_xor(ps, o);
        ns += __shfl_xor(ns, o);
    }
    if (lane == 0) { out[gw] = ps; out[NB + gw] = ns; }
}

extern "C" void kernel_launch(void* const* d_in, const int* in_sizes, int n_in,
                              void* d_out, int out_size, void* d_ws, size_t ws_size,
                              hipStream_t stream) {
    const int*   un    = (const int*)d_in[0];
    const int*   pn    = (const int*)d_in[1];
    const int*   ngn   = (const int*)d_in[2];
    const int*   ug    = (const int*)d_in[3];
    const int*   eidx  = (const int*)d_in[4];
    const float* uwm   = (const float*)d_in[5];
    const float* feats[3] = { (const float*)d_in[6], (const float*)d_in[7], (const float*)d_in[8] };
    const int    featK[3] = { 1024, 128, 100 };
    const float* prefs[3] = { (const float*)d_in[9], (const float*)d_in[10], (const float*)d_in[11] };
    const float* W1[3] = { (const float*)d_in[12], (const float*)d_in[16], (const float*)d_in[20] };
    const float* b1[3] = { (const float*)d_in[13], (const float*)d_in[17], (const float*)d_in[21] };
    const float* W2[3] = { (const float*)d_in[14], (const float*)d_in[18], (const float*)d_in[22] };
    const float* b2[3] = { (const float*)d_in[15], (const float*)d_in[19], (const float*)d_in[23] };
    const float* wu    = (const float*)d_in[24];
    float* out = (float*)d_out;

    const int* esrc = eidx;
    const int* edst = eidx + NE;

    // workspace layout
    char* ws = (char*)d_ws;
    size_t off = 0;
    auto alloc = [&](size_t bytes) { void* p = ws + off; off = (off + bytes + 255) & ~(size_t)255; return p; };
    unsigned* deg    = (unsigned*)alloc(NN * sizeof(unsigned));   // reused as CSR cursor
    float*    dinv   = (float*)alloc(NN * sizeof(float));
    int*      rowptr = (int*)alloc((NN + 1) * sizeof(int));
    int2*     csr    = (int2*)alloc((size_t)NE * sizeof(int2));
    float*    X      = (float*)alloc((size_t)NN * XW * sizeof(float));  // becomes REP after conv2
    float*    H      = (float*)alloc((size_t)NN * XW * sizeof(float));  // head doubles as bf16 hidden
    float*    UR     = (float*)alloc((size_t)NUSER * DIMV * sizeof(float));
    float*    RES    = (float*)alloc((size_t)NN * DIMV * sizeof(float));
    short*    hidden = (short*)H;   // 30000*256 bf16 = 15.4 MB < 46 MB

    // 1. degrees + CSR build
    hipMemsetAsync(deg, 0, NN * sizeof(unsigned), stream);
    k_deg<<<(NE + 255) / 256, 256, 0, stream>>>(esrc, deg);
    k_dinv<<<(NN + 255) / 256, 256, 0, stream>>>(deg, dinv);
    k_scan<<<1, 1024, 0, stream>>>(deg, rowptr);
    hipMemsetAsync(deg, 0, NN * sizeof(unsigned), stream);
    k_fill<<<(NE + 255) / 256, 256, 0, stream>>>(esrc, edst, dinv, rowptr, deg, csr);

    // 2. per-modality MLP (MFMA bf16) -> item rows of X (l2-normalized)
    for (int m = 0; m < 3; ++m) {
        gemm1_mfma<<<(NITEM + 127) / 128, 256, 0, stream>>>(feats[m], W1[m], b1[m], hidden,
                                                            NITEM, featK[m]);
        gemm2_mfma<<<(NITEM + 127) / 128, 256, 0, stream>>>(hidden, W2[m], b2[m], X,
                                                            NITEM, m);
    }
    k_users_norm<<<(NUSER * 3 * 64 + 255) / 256, 256, 0, stream>>>(prefs[0], prefs[1], prefs[2], X);

    // 3. conv1: H = A * X
    k_spmm<false><<<(NN + 3) / 4, 256, 0, stream>>>(rowptr, csr, X, H, nullptr);

    // 4. conv2 fused: X(=REP) = X + H + A * H
    k_spmm<true><<<(NN + 3) / 4, 256, 0, stream>>>(rowptr, csr, H, X, X);

    // 5-7. combine, user-graph, scores
    k_combine<<<(NN * DIMV + 255) / 256, 256, 0, stream>>>(X, wu, UR, RES);
    k_usergraph<<<(NUSER * DIMV + 255) / 256, 256, 0, stream>>>(UR, ug, uwm, RES);
    k_scores<<<(NB * 64 + 255) / 256, 256, 0, stream>>>(RES, un, pn, ngn, out);
}

// Round 4
// 573.634 us; speedup vs baseline: 10.3217x; 1.1884x over previous
//
#include <hip/hip_runtime.h>
#include <hip/hip_bf16.h>
#include <math.h>

#define NUSER 30000
#define NITEM 30000
#define NN    60000
#define NE    1000000
#define DIMV  64
#define XW    192
#define HIDW  256
#define NB    2048
#define KNB   10
#define MPAD  30080    // NITEM padded to 128

typedef __attribute__((ext_vector_type(8))) short bf16x8;
typedef __attribute__((ext_vector_type(4))) float f32x4;

__device__ __forceinline__ short f2bf(float f) {
    union { float f; unsigned u; } v; v.f = f;
    unsigned r = v.u + 0x7fff + ((v.u >> 16) & 1);
    return (short)(r >> 16);
}
__device__ __forceinline__ float bflo(unsigned v) { return __int_as_float(v << 16); }
__device__ __forceinline__ float bfhi(unsigned v) { return __int_as_float(v & 0xffff0000u); }
__device__ __forceinline__ unsigned pack2(float a, float b) {
    return (unsigned)(unsigned short)f2bf(a) | ((unsigned)(unsigned short)f2bf(b) << 16);
}
__device__ __forceinline__ void async16(void* lds, const void* g) {
    __builtin_amdgcn_global_load_lds(
        (const __attribute__((address_space(1))) unsigned*)g,
        (__attribute__((address_space(3))) unsigned*)lds, 16, 0, 0);
}

// ================= degree / CSR =================
__global__ void k_deg(const int* __restrict__ src, unsigned* __restrict__ deg) {
    int e = blockIdx.x * blockDim.x + threadIdx.x;
    if (e < NE) atomicAdd(&deg[src[e]], 1u);
}
__global__ void k_dinv(const unsigned* __restrict__ deg, float* __restrict__ dinv) {
    int i = blockIdx.x * blockDim.x + threadIdx.x;
    if (i < NN) { unsigned d = deg[i]; dinv[i] = d ? rsqrtf((float)d) : 0.f; }
}
__global__ __launch_bounds__(1024)
void k_scan(const unsigned* __restrict__ deg, int* __restrict__ rowptr) {
    __shared__ int sums[1024];
    const int T = 1024, CH = (NN + T - 1) / T;
    int t = threadIdx.x;
    int lo = t * CH, hi = min(lo + CH, NN);
    int s = 0;
    for (int i = lo; i < hi; ++i) s += (int)deg[i];
    sums[t] = s;
    __syncthreads();
    for (int o = 1; o < T; o <<= 1) {
        int v = (t >= o) ? sums[t - o] : 0;
        __syncthreads();
        sums[t] += v;
        __syncthreads();
    }
    int run = sums[t] - s;
    for (int i = lo; i < hi; ++i) { rowptr[i] = run; run += (int)deg[i]; }
    if (t == T - 1) rowptr[NN] = run;
}
__global__ void k_fill(const int* __restrict__ src, const int* __restrict__ dst,
                       const float* __restrict__ dinv, const int* __restrict__ rowptr,
                       unsigned* __restrict__ cursor, int2* __restrict__ csr) {
    int e = blockIdx.x * blockDim.x + threadIdx.x;
    if (e >= NE) return;
    int s = src[e], d = dst[e];
    int pos = (int)atomicAdd(&cursor[d], 1u);
    int2 ew;
    ew.x = s;
    ew.y = __float_as_int(dinv[s] * dinv[d]);
    csr[rowptr[d] + pos] = ew;
}

// ================= fp32 -> bf16 convert with pad (9 jobs, one launch) ==========
struct CvtArgs { const float* src[9]; short* dst[9]; };
__constant__ __device__ const int CROWS[9] = {30000,30000,30000,256,256,256,64,64,64};
__constant__ __device__ const int CCOLS[9] = {1024,128,100,1024,128,100,256,256,256};
__constant__ __device__ const int CCPAD[9] = {1024,128,128,1024,128,128,256,256,256};
__constant__ __device__ const int CPRE[10] = {0,7700480,8663040,9625600,9691136,
                                              9699328,9707520,9711616,9715712,9719808};
#define CVT_TOTAL 9719808

__global__ __launch_bounds__(256)
void k_convert(CvtArgs a) {
    int cid = blockIdx.x * 256 + threadIdx.x;
    if (cid >= CVT_TOTAL) return;
    int j = 0;
    while (cid >= CPRE[j + 1]) ++j;
    int local = cid - CPRE[j];
    int cpr = CCPAD[j] >> 2;
    int r = local / cpr, c4 = local - r * cpr;
    int col = c4 * 4;
    int rows = CROWS[j], cols = CCOLS[j];
    short o0 = 0, o1 = 0, o2 = 0, o3 = 0;
    if (r < rows) {
        const float* s = a.src[j] + (size_t)r * cols + col;
        if (col + 4 <= cols) {
            float4 f = *(const float4*)s;
            o0 = f2bf(f.x); o1 = f2bf(f.y); o2 = f2bf(f.z); o3 = f2bf(f.w);
        } else {
            if (col + 0 < cols) o0 = f2bf(s[0]);
            if (col + 1 < cols) o1 = f2bf(s[1]);
            if (col + 2 < cols) o2 = f2bf(s[2]);
            if (col + 3 < cols) o3 = f2bf(s[3]);
        }
    }
    *(short4*)(a.dst[j] + (size_t)r * CCPAD[j] + col) = make_short4(o0, o1, o2, o3);
}

// ================= LDS helpers (XOR swizzle, [R][64] bf16 tiles) =================
__device__ __forceinline__ bf16x8 ldfrag(const short* lds, int row, int kbyte) {
    int off = (row * 128 + kbyte) ^ ((row & 7) << 4);
    return *(const bf16x8*)((const char*)lds + off);
}
// stage one wave-batch of chunks: chunk c -> LDS byte c*16, global slot pre-inverse-swizzled
#define STAGE_TILE(SMEM, BASEPTR, LDK, ROWOFF, K0, NITERS)                          \
    _Pragma("unroll")                                                                \
    for (int i_ = 0; i_ < (NITERS); ++i_) {                                          \
        int c_ = i_ * 256 + wave * 64 + lane;                                        \
        int r_ = c_ >> 3, slot_ = c_ & 7;                                            \
        int ss_ = slot_ ^ (r_ & 7);                                                  \
        const char* gp_ = (const char*)((BASEPTR) + (size_t)((ROWOFF) + r_) * (LDK)  \
                                        + (K0)) + ss_ * 16;                          \
        async16(&(SMEM)[(i_ * 256 + wave * 64) * 8], gp_);                           \
    }

// ================= GEMM1 fused (3 modalities): hidden = lrelu(A*W1^T + b1) =======
struct G1Args { const short* A[3]; const short* W[3]; const float* bias[3];
                short* C[3]; int K[3]; };
__global__ __launch_bounds__(256)
void gemm1_mfma(G1Args g) {
    __shared__ __align__(16) short sA[128 * 64];
    __shared__ __align__(16) short sB[128 * 64];
    int m = blockIdx.z;
    int K = g.K[m];
    const short* A = g.A[m];
    const short* W = g.W[m];
    int lane = threadIdx.x & 63, wave = threadIdx.x >> 6;
    int wr = wave >> 1, wc = wave & 1;
    int lane15 = lane & 15, lhi = lane >> 4;
    int row0 = blockIdx.x * 128, col0 = blockIdx.y * 128;
    f32x4 acc[4][4] = {};
    for (int t = 0; t < (K >> 6); ++t) {
        int k0 = t * 64;
        STAGE_TILE(sA, A, K, row0, k0, 4)
        STAGE_TILE(sB, W, K, col0, k0, 4)
        __syncthreads();
        #pragma unroll
        for (int ks = 0; ks < 2; ++ks) {
            int kb = ks * 64 + lhi * 16;
            bf16x8 a[4], b[4];
            #pragma unroll
            for (int mi = 0; mi < 4; ++mi) a[mi] = ldfrag(sA, wr * 64 + mi * 16 + lane15, kb);
            #pragma unroll
            for (int ni = 0; ni < 4; ++ni) b[ni] = ldfrag(sB, wc * 64 + ni * 16 + lane15, kb);
            #pragma unroll
            for (int mi = 0; mi < 4; ++mi)
                #pragma unroll
                for (int ni = 0; ni < 4; ++ni)
                    acc[mi][ni] = __builtin_amdgcn_mfma_f32_16x16x32_bf16(a[mi], b[ni], acc[mi][ni], 0, 0, 0);
        }
        __syncthreads();
    }
    short* C = g.C[m];
    const float* bias = g.bias[m];
    #pragma unroll
    for (int mi = 0; mi < 4; ++mi) {
        int grow0 = row0 + wr * 64 + mi * 16 + lhi * 4;
        #pragma unroll
        for (int ni = 0; ni < 4; ++ni) {
            int gcol = col0 + wc * 64 + ni * 16 + lane15;
            float bv = bias[gcol];
            #pragma unroll
            for (int r = 0; r < 4; ++r) {
                float v = acc[mi][ni][r] + bv;
                v = v > 0.f ? v : 0.01f * v;
                C[(size_t)(grow0 + r) * HIDW + gcol] = f2bf(v);
            }
        }
    }
}

// ================= GEMM2 fused + l2norm -> item rows of X (fp32 + bf16) ==========
struct G2Args { const short* A[3]; const short* W[3]; const float* bias[3]; };
__global__ __launch_bounds__(256)
void gemm2_mfma(G2Args g, float* __restrict__ X, short* __restrict__ Xb) {
    __shared__ __align__(16) short sA[128 * 64];
    __shared__ __align__(16) short sB[64 * 64];
    int m = blockIdx.z;
    const short* A = g.A[m];
    const short* W = g.W[m];
    int lane = threadIdx.x & 63, wave = threadIdx.x >> 6;
    int lane15 = lane & 15, lhi = lane >> 4;
    int row0 = blockIdx.x * 128;
    const int K = HIDW;
    f32x4 acc[2][4] = {};
    for (int t = 0; t < 4; ++t) {
        int k0 = t * 64;
        STAGE_TILE(sA, A, K, row0, k0, 4)
        STAGE_TILE(sB, W, K, 0, k0, 2)
        __syncthreads();
        #pragma unroll
        for (int ks = 0; ks < 2; ++ks) {
            int kb = ks * 64 + lhi * 16;
            bf16x8 a[2], b[4];
            #pragma unroll
            for (int mi = 0; mi < 2; ++mi) a[mi] = ldfrag(sA, wave * 32 + mi * 16 + lane15, kb);
            #pragma unroll
            for (int ni = 0; ni < 4; ++ni) b[ni] = ldfrag(sB, ni * 16 + lane15, kb);
            #pragma unroll
            for (int mi = 0; mi < 2; ++mi)
                #pragma unroll
                for (int ni = 0; ni < 4; ++ni)
                    acc[mi][ni] = __builtin_amdgcn_mfma_f32_16x16x32_bf16(a[mi], b[ni], acc[mi][ni], 0, 0, 0);
        }
        __syncthreads();
    }
    const float* bias = g.bias[m];
    #pragma unroll
    for (int mi = 0; mi < 2; ++mi) {
        float v[4][4];
        float sumsq[4] = {};
        #pragma unroll
        for (int ni = 0; ni < 4; ++ni) {
            float bv = bias[ni * 16 + lane15];
            #pragma unroll
            for (int r = 0; r < 4; ++r) {
                float x = acc[mi][ni][r] + bv;
                v[ni][r] = x;
                sumsq[r] += x * x;
            }
        }
        #pragma unroll
        for (int r = 0; r < 4; ++r) {
            float s = sumsq[r];
            s += __shfl_xor(s, 1); s += __shfl_xor(s, 2);
            s += __shfl_xor(s, 4); s += __shfl_xor(s, 8);
            sumsq[r] = 1.f / fmaxf(sqrtf(s), 1e-12f);
        }
        int grow0 = row0 + wave * 32 + mi * 16 + lhi * 4;
        #pragma unroll
        for (int r = 0; r < 4; ++r) {
            int grow = grow0 + r;
            if (grow < NITEM) {
                float sc = sumsq[r];
                size_t o = (size_t)(NUSER + grow) * XW + m * DIMV;
                #pragma unroll
                for (int ni = 0; ni < 4; ++ni) {
                    float val = v[ni][r] * sc;
                    X[o + ni * 16 + lane15] = val;
                    Xb[o + ni * 16 + lane15] = f2bf(val);
                }
            }
        }
    }
}

// ================= user rows: l2norm(pref) -> X fp32 + bf16 =================
__global__ void k_users_norm(const float* __restrict__ vp, const float* __restrict__ ap,
                             const float* __restrict__ tp, float* __restrict__ X,
                             short* __restrict__ Xb) {
    int gw = (blockIdx.x * blockDim.x + threadIdx.x) >> 6;
    int lane = threadIdx.x & 63;
    if (gw >= NUSER * 3) return;
    int u = gw / 3, m = gw % 3;
    const float* p = (m == 0) ? vp : (m == 1) ? ap : tp;
    float v = p[(size_t)u * DIMV + lane];
    float s = v * v;
    for (int o = 32; o > 0; o >>= 1) s += __shfl_xor(s, o);
    float sc = 1.f / fmaxf(sqrtf(s), 1e-12f);
    size_t o = (size_t)u * XW + m * DIMV + lane;
    float val = v * sc;
    X[o] = val;
    Xb[o] = f2bf(val);
}

// ================= gather SpMM over bf16 mirror =================
// MODE 0: OUT = A*INB (fp32) and OUTB = bf16(OUT)
// MODE 1: OUT = Xf + Hf + A*INB (fp32), in-place safe (OUT==Xf)
template<int MODE>
__global__ __launch_bounds__(256)
void k_spmm(const int* __restrict__ rowptr, const int2* __restrict__ csr,
            const short* __restrict__ INB, float* __restrict__ OUT,
            short* __restrict__ OUTB, const float* __restrict__ Xf,
            const float* __restrict__ Hf) {
    int n = blockIdx.x * 4 + (threadIdx.x >> 6);
    int l = threadIdx.x & 63;
    if (n >= NN) return;
    int lo = rowptr[n], hi = rowptr[n + 1];
    bool half = l < 32;
    float a0 = 0.f, a1 = 0.f, b0 = 0.f, b1 = 0.f;
    for (int j = lo; j < hi; ++j) {
        int2 ew = csr[j];
        float w = __int_as_float(ew.y);
        const unsigned* p = (const unsigned*)(INB + (size_t)ew.x * XW);
        unsigned v = p[l];
        a0 += w * bflo(v); a1 += w * bfhi(v);
        if (half) {
            unsigned v2 = p[64 + l];
            b0 += w * bflo(v2); b1 += w * bfhi(v2);
        }
    }
    size_t o = (size_t)n * XW;
    if (MODE == 1) {
        const float2* xp = (const float2*)(Xf + o);
        const float2* hp = (const float2*)(Hf + o);
        float2 x0 = xp[l], h0 = hp[l];
        a0 += x0.x + h0.x; a1 += x0.y + h0.y;
        if (half) {
            float2 x1 = xp[64 + l], h1 = hp[64 + l];
            b0 += x1.x + h1.x; b1 += x1.y + h1.y;
        }
    }
    float2* op = (float2*)(OUT + o);
    op[l] = make_float2(a0, a1);
    if (half) op[64 + l] = make_float2(b0, b1);
    if (MODE == 0) {
        unsigned* ob = (unsigned*)(OUTB + o);
        ob[l] = pack2(a0, a1);
        if (half) ob[64 + l] = pack2(b0, b1);
    }
}

// ================= combine / usergraph / scores =================
__global__ void k_combine(const float* __restrict__ REP, const float* __restrict__ wu,
                          float* __restrict__ UR, float* __restrict__ RES) {
    int t = blockIdx.x * blockDim.x + threadIdx.x;
    if (t >= NN * DIMV) return;
    int n = t >> 6, d = t & 63;
    const float* r = REP + (size_t)n * XW;
    float r0 = r[d], r1 = r[DIMV + d], r2 = r[2 * DIMV + d];
    if (n < NUSER) {
        float w0 = wu[n * 3 + 0], w1 = wu[n * 3 + 1], w2 = wu[n * 3 + 2];
        UR[(size_t)n * DIMV + d] = r0 * w0 + r1 * w1 + r2 * w2;
    } else {
        RES[(size_t)n * DIMV + d] = (r0 + r1 + r2) * (1.f / 3.f);
    }
}
__global__ void k_usergraph(const float* __restrict__ UR, const int* __restrict__ g,
                            const float* __restrict__ w, float* __restrict__ RES) {
    int t = blockIdx.x * blockDim.x + threadIdx.x;
    if (t >= NUSER * DIMV) return;
    int n = t >> 6, d = t & 63;
    float acc = UR[(size_t)n * DIMV + d];
    for (int k = 0; k < KNB; ++k) {
        int nb = g[n * KNB + k];
        acc += w[n * KNB + k] * UR[(size_t)nb * DIMV + d];
    }
    RES[(size_t)n * DIMV + d] = acc;
}
__global__ void k_scores(const float* __restrict__ RES, const int* __restrict__ un,
                         const int* __restrict__ pn, const int* __restrict__ nn,
                         float* __restrict__ out) {
    int gw = (blockIdx.x * blockDim.x + threadIdx.x) >> 6;
    int lane = threadIdx.x & 63;
    if (gw >= NB) return;
    int u = un[gw], p = pn[gw], ng = nn[gw];
    float uv = RES[(size_t)u * DIMV + lane];
    float ps = uv * RES[(size_t)p * DIMV + lane];
    float ns = uv * RES[(size_t)ng * DIMV + lane];
    for (int o = 32; o > 0; o >>= 1) {
        ps += __shfl_xor(ps, o);
        ns += __shfl_xor(ns, o);
    }
    if (lane == 0) { out[gw] = ps; out[NB + gw] = ns; }
}

extern "C" void kernel_launch(void* const* d_in, const int* in_sizes, int n_in,
                              void* d_out, int out_size, void* d_ws, size_t ws_size,
                              hipStream_t stream) {
    const int*   un    = (const int*)d_in[0];
    const int*   pn    = (const int*)d_in[1];
    const int*   ngn   = (const int*)d_in[2];
    const int*   ug    = (const int*)d_in[3];
    const int*   eidx  = (const int*)d_in[4];
    const float* uwm   = (const float*)d_in[5];
    const float* feats[3] = { (const float*)d_in[6], (const float*)d_in[7], (const float*)d_in[8] };
    const float* prefs[3] = { (const float*)d_in[9], (const float*)d_in[10], (const float*)d_in[11] };
    const float* W1[3] = { (const float*)d_in[12], (const float*)d_in[16], (const float*)d_in[20] };
    const float* b1[3] = { (const float*)d_in[13], (const float*)d_in[17], (const float*)d_in[21] };
    const float* W2[3] = { (const float*)d_in[14], (const float*)d_in[18], (const float*)d_in[22] };
    const float* b2[3] = { (const float*)d_in[15], (const float*)d_in[19], (const float*)d_in[23] };
    const float* wu    = (const float*)d_in[24];
    float* out = (float*)d_out;

    const int* esrc = eidx;
    const int* edst = eidx + NE;

    // ---- workspace (phase-aliased) ----
    char* ws = (char*)d_ws;
    size_t off = 0;
    auto alloc = [&](size_t bytes) { void* p = ws + off; off = (off + bytes + 255) & ~(size_t)255; return p; };
    unsigned* deg    = (unsigned*)alloc(NN * 4);
    float*    dinv   = (float*)alloc(NN * 4);
    int*      rowptr = (int*)alloc((NN + 1) * 4);
    int2*     csr    = (int2*)alloc((size_t)NE * 8);
    // region1: Ab (77.0 MB) until gemm1; then X fp32 (46.08) + Xb bf16 (23.04)
    char* region1 = (char*)alloc((size_t)MPAD * 1280 * 2);
    short* Ab0 = (short*)region1;
    short* Ab1 = (short*)(region1 + (size_t)MPAD * 1024 * 2);
    short* Ab2 = (short*)(region1 + (size_t)MPAD * (1024 + 128) * 2);
    float* X   = (float*)region1;
    short* Xb  = (short*)(region1 + (size_t)NN * XW * 4);
    float* H   = (float*)alloc((size_t)NN * XW * 4);
    // region2: hidden (3x 30080x256 bf16 = 46.2 MB) until gemm2; then RES+UR+Hb
    char* region2 = (char*)alloc((size_t)3 * MPAD * HIDW * 2);
    short* hid[3] = { (short*)region2,
                      (short*)(region2 + (size_t)MPAD * HIDW * 2),
                      (short*)(region2 + (size_t)2 * MPAD * HIDW * 2) };
    float* RES = (float*)region2;                                   // 15.36 MB
    float* UR  = (float*)(region2 + (size_t)NN * DIMV * 4 + 40960); // after RES (seg0 is 15.40 MB)
    short* Hb  = (short*)(region2 + (size_t)NN * DIMV * 4 + 40960 + (size_t)NUSER * DIMV * 4);
    short* w1b = (short*)alloc((size_t)256 * 1280 * 2);
    short* w1s[3] = { w1b, w1b + 256 * 1024, w1b + 256 * (1024 + 128) };
    short* w2b = (short*)alloc((size_t)3 * 64 * HIDW * 2);
    short* w2s[3] = { w2b, w2b + 64 * HIDW, w2b + 2 * 64 * HIDW };

    // ---- 1. convert fp32->bf16 (padded) ----
    CvtArgs ca;
    ca.src[0] = feats[0]; ca.src[1] = feats[1]; ca.src[2] = feats[2];
    ca.src[3] = W1[0];    ca.src[4] = W1[1];    ca.src[5] = W1[2];
    ca.src[6] = W2[0];    ca.src[7] = W2[1];    ca.src[8] = W2[2];
    ca.dst[0] = Ab0; ca.dst[1] = Ab1; ca.dst[2] = Ab2;
    ca.dst[3] = w1s[0]; ca.dst[4] = w1s[1]; ca.dst[5] = w1s[2];
    ca.dst[6] = w2s[0]; ca.dst[7] = w2s[1]; ca.dst[8] = w2s[2];
    k_convert<<<CVT_TOTAL / 256, 256, 0, stream>>>(ca);

    // ---- 2. CSR build ----
    hipMemsetAsync(deg, 0, NN * 4, stream);
    k_deg<<<(NE + 255) / 256, 256, 0, stream>>>(esrc, deg);
    k_dinv<<<(NN + 255) / 256, 256, 0, stream>>>(deg, dinv);
    k_scan<<<1, 1024, 0, stream>>>(deg, rowptr);
    hipMemsetAsync(deg, 0, NN * 4, stream);
    k_fill<<<(NE + 255) / 256, 256, 0, stream>>>(esrc, edst, dinv, rowptr, deg, csr);

    // ---- 3. gemm1 fused (reads Ab, writes hidden) ----
    G1Args g1;
    for (int m = 0; m < 3; ++m) { g1.bias[m] = b1[m]; g1.C[m] = hid[m]; g1.W[m] = w1s[m]; }
    g1.A[0] = Ab0; g1.A[1] = Ab1; g1.A[2] = Ab2;
    g1.K[0] = 1024; g1.K[1] = 128; g1.K[2] = 128;
    gemm1_mfma<<<dim3(MPAD / 128, 2, 3), 256, 0, stream>>>(g1);

    // ---- 4. gemm2 fused (reads hidden, writes X/Xb over dead Ab) ----
    G2Args g2;
    for (int m = 0; m < 3; ++m) { g2.A[m] = hid[m]; g2.W[m] = w2s[m]; g2.bias[m] = b2[m]; }
    gemm2_mfma<<<dim3(MPAD / 128, 1, 3), 256, 0, stream>>>(g2, X, Xb);
    k_users_norm<<<(NUSER * 3 * 64 + 255) / 256, 256, 0, stream>>>(prefs[0], prefs[1], prefs[2], X, Xb);

    // ---- 5. conv1: H = A*X (gather Xb), also write Hb ----
    k_spmm<0><<<(NN + 3) / 4, 256, 0, stream>>>(rowptr, csr, Xb, H, Hb, nullptr, nullptr);

    // ---- 6. conv2 fused: X(=REP) = X + H + A*H (gather Hb) ----
    k_spmm<1><<<(NN + 3) / 4, 256, 0, stream>>>(rowptr, csr, Hb, X, nullptr, X, H);

    // ---- 7. combine / usergraph / scores ----
    k_combine<<<(NN * DIMV + 255) / 256, 256, 0, stream>>>(X, wu, UR, RES);
    k_usergraph<<<(NUSER * DIMV + 255) / 256, 256, 0, stream>>>(UR, ug, uwm, RES);
    k_scores<<<(NB * 64 + 255) / 256, 256, 0, stream>>>(RES, un, pn, ngn, out);
}

// Round 5
// 363.310 us; speedup vs baseline: 16.2971x; 1.5789x over previous
//
#include <hip/hip_runtime.h>
#include <hip/hip_bf16.h>
#include <math.h>

#define NUSER 30000
#define NITEM 30000
#define NN    60000
#define NE    1000000
#define DIMV  64
#define XW    192
#define HIDW  256
#define NB    2048
#define KNB   10
#define MPAD  30080
#define NCH   235      // ceil(NN/256)

typedef __attribute__((ext_vector_type(8))) short bf16x8;
typedef __attribute__((ext_vector_type(4))) float f32x4;

__device__ __forceinline__ short f2bf(float f) {
    union { float f; unsigned u; } v; v.f = f;
    unsigned r = v.u + 0x7fff + ((v.u >> 16) & 1);
    return (short)(r >> 16);
}
__device__ __forceinline__ float bflo(unsigned v) { return __int_as_float(v << 16); }
__device__ __forceinline__ float bfhi(unsigned v) { return __int_as_float(v & 0xffff0000u); }
__device__ __forceinline__ unsigned pack2(float a, float b) {
    return (unsigned)(unsigned short)f2bf(a) | ((unsigned)(unsigned short)f2bf(b) << 16);
}
__device__ __forceinline__ void async16(void* lds, const void* g) {
    __builtin_amdgcn_global_load_lds(
        (const __attribute__((address_space(1))) unsigned*)g,
        (__attribute__((address_space(3))) unsigned*)lds, 16, 0, 0);
}

// ================= degree / CSR =================
__global__ void k_deg(const int* __restrict__ src, unsigned* __restrict__ deg) {
    int e = blockIdx.x * blockDim.x + threadIdx.x;
    if (e < NE) atomicAdd(&deg[src[e]], 1u);
}
__global__ void k_dinv(const unsigned* __restrict__ deg, float* __restrict__ dinv) {
    int i = blockIdx.x * blockDim.x + threadIdx.x;
    if (i < NN) { unsigned d = deg[i]; dinv[i] = d ? rsqrtf((float)d) : 0.f; }
}
// ---- 3-stage block scan: deg -> rowptr ----
__global__ __launch_bounds__(256)
void k_bsum(const unsigned* __restrict__ deg, int* __restrict__ bsum) {
    __shared__ int red[4];
    int g = blockIdx.x * 256 + threadIdx.x;
    int v = (g < NN) ? (int)deg[g] : 0;
    for (int o = 32; o > 0; o >>= 1) v += __shfl_down(v, o);
    int lane = threadIdx.x & 63, wave = threadIdx.x >> 6;
    if (lane == 0) red[wave] = v;
    __syncthreads();
    if (threadIdx.x == 0) bsum[blockIdx.x] = red[0] + red[1] + red[2] + red[3];
}
__global__ __launch_bounds__(256)
void k_bscan(const int* __restrict__ bsum, int* __restrict__ bscan) {
    __shared__ int s[256];
    int t = threadIdx.x;
    int v = (t < NCH) ? bsum[t] : 0;
    s[t] = v;
    __syncthreads();
    for (int o = 1; o < 256; o <<= 1) {
        int u = (t >= o) ? s[t - o] : 0;
        __syncthreads();
        s[t] += u;
        __syncthreads();
    }
    if (t < NCH) bscan[t] = s[t] - v;   // exclusive
}
__global__ __launch_bounds__(256)
void k_rowptr(const unsigned* __restrict__ deg, const int* __restrict__ bscan,
              int* __restrict__ rowptr) {
    __shared__ int s[256];
    int g = blockIdx.x * 256 + threadIdx.x, t = threadIdx.x;
    int v = (g < NN) ? (int)deg[g] : 0;
    s[t] = v;
    __syncthreads();
    for (int o = 1; o < 256; o <<= 1) {
        int u = (t >= o) ? s[t - o] : 0;
        __syncthreads();
        s[t] += u;
        __syncthreads();
    }
    int base = bscan[blockIdx.x];
    if (g < NN) rowptr[g] = base + s[t] - v;
    if (g == NN - 1) rowptr[NN] = base + s[t];
}
__global__ void k_fill(const int* __restrict__ src, const int* __restrict__ dst,
                       const float* __restrict__ dinv, const int* __restrict__ rowptr,
                       unsigned* __restrict__ cursor, int2* __restrict__ csr) {
    int e = blockIdx.x * blockDim.x + threadIdx.x;
    if (e >= NE) return;
    int s = src[e], d = dst[e];
    int pos = (int)atomicAdd(&cursor[d], 1u);
    int2 ew;
    ew.x = s;
    ew.y = __float_as_int(dinv[s] * dinv[d]);
    csr[rowptr[d] + pos] = ew;
}

// ================= fp32 -> bf16 convert with pad =================
struct CvtArgs { const float* src[9]; short* dst[9]; };
__constant__ __device__ const int CROWS[9] = {30000,30000,30000,256,256,256,64,64,64};
__constant__ __device__ const int CCOLS[9] = {1024,128,100,1024,128,100,256,256,256};
__constant__ __device__ const int CCPAD[9] = {1024,128,128,1024,128,128,256,256,256};
__constant__ __device__ const int CPRE[10] = {0,7700480,8663040,9625600,9691136,
                                              9699328,9707520,9711616,9715712,9719808};
#define CVT_TOTAL 9719808

__global__ __launch_bounds__(256)
void k_convert(CvtArgs a) {
    int cid = blockIdx.x * 256 + threadIdx.x;
    if (cid >= CVT_TOTAL) return;
    int j = 0;
    while (cid >= CPRE[j + 1]) ++j;
    int local = cid - CPRE[j];
    int cpr = CCPAD[j] >> 2;
    int r = local / cpr, c4 = local - r * cpr;
    int col = c4 * 4;
    int rows = CROWS[j], cols = CCOLS[j];
    short o0 = 0, o1 = 0, o2 = 0, o3 = 0;
    if (r < rows) {
        const float* s = a.src[j] + (size_t)r * cols + col;
        if (col + 4 <= cols) {
            float4 f = *(const float4*)s;
            o0 = f2bf(f.x); o1 = f2bf(f.y); o2 = f2bf(f.z); o3 = f2bf(f.w);
        } else {
            if (col + 0 < cols) o0 = f2bf(s[0]);
            if (col + 1 < cols) o1 = f2bf(s[1]);
            if (col + 2 < cols) o2 = f2bf(s[2]);
            if (col + 3 < cols) o3 = f2bf(s[3]);
        }
    }
    *(short4*)(a.dst[j] + (size_t)r * CCPAD[j] + col) = make_short4(o0, o1, o2, o3);
}

// ================= LDS helpers =================
__device__ __forceinline__ bf16x8 ldfrag(const short* lds, int row, int kbyte) {
    int off = (row * 128 + kbyte) ^ ((row & 7) << 4);
    return *(const bf16x8*)((const char*)lds + off);
}
#define STAGE_TILE(SMEM, BASEPTR, LDK, ROWOFF, K0, NITERS)                          \
    _Pragma("unroll")                                                                \
    for (int i_ = 0; i_ < (NITERS); ++i_) {                                          \
        int c_ = i_ * 256 + wave * 64 + lane;                                        \
        int r_ = c_ >> 3, slot_ = c_ & 7;                                            \
        int ss_ = slot_ ^ (r_ & 7);                                                  \
        const char* gp_ = (const char*)((BASEPTR) + (size_t)((ROWOFF) + r_) * (LDK)  \
                                        + (K0)) + ss_ * 16;                          \
        async16(&(SMEM)[(i_ * 256 + wave * 64) * 8], gp_);                           \
    }

// ================= GEMM1 fused =================
struct G1Args { const short* A[3]; const short* W[3]; const float* bias[3];
                short* C[3]; int K[3]; };
__global__ __launch_bounds__(256)
void gemm1_mfma(G1Args g) {
    __shared__ __align__(16) short sA[128 * 64];
    __shared__ __align__(16) short sB[128 * 64];
    int m = blockIdx.z;
    int K = g.K[m];
    const short* A = g.A[m];
    const short* W = g.W[m];
    int lane = threadIdx.x & 63, wave = threadIdx.x >> 6;
    int wr = wave >> 1, wc = wave & 1;
    int lane15 = lane & 15, lhi = lane >> 4;
    int row0 = blockIdx.x * 128, col0 = blockIdx.y * 128;
    f32x4 acc[4][4] = {};
    for (int t = 0; t < (K >> 6); ++t) {
        int k0 = t * 64;
        STAGE_TILE(sA, A, K, row0, k0, 4)
        STAGE_TILE(sB, W, K, col0, k0, 4)
        __syncthreads();
        #pragma unroll
        for (int ks = 0; ks < 2; ++ks) {
            int kb = ks * 64 + lhi * 16;
            bf16x8 a[4], b[4];
            #pragma unroll
            for (int mi = 0; mi < 4; ++mi) a[mi] = ldfrag(sA, wr * 64 + mi * 16 + lane15, kb);
            #pragma unroll
            for (int ni = 0; ni < 4; ++ni) b[ni] = ldfrag(sB, wc * 64 + ni * 16 + lane15, kb);
            #pragma unroll
            for (int mi = 0; mi < 4; ++mi)
                #pragma unroll
                for (int ni = 0; ni < 4; ++ni)
                    acc[mi][ni] = __builtin_amdgcn_mfma_f32_16x16x32_bf16(a[mi], b[ni], acc[mi][ni], 0, 0, 0);
        }
        __syncthreads();
    }
    short* C = g.C[m];
    const float* bias = g.bias[m];
    #pragma unroll
    for (int mi = 0; mi < 4; ++mi) {
        int grow0 = row0 + wr * 64 + mi * 16 + lhi * 4;
        #pragma unroll
        for (int ni = 0; ni < 4; ++ni) {
            int gcol = col0 + wc * 64 + ni * 16 + lane15;
            float bv = bias[gcol];
            #pragma unroll
            for (int r = 0; r < 4; ++r) {
                float v = acc[mi][ni][r] + bv;
                v = v > 0.f ? v : 0.01f * v;
                C[(size_t)(grow0 + r) * HIDW + gcol] = f2bf(v);
            }
        }
    }
}

// ================= GEMM2 fused + l2norm =================
struct G2Args { const short* A[3]; const short* W[3]; const float* bias[3]; };
__global__ __launch_bounds__(256)
void gemm2_mfma(G2Args g, float* __restrict__ X, short* __restrict__ Xb) {
    __shared__ __align__(16) short sA[128 * 64];
    __shared__ __align__(16) short sB[64 * 64];
    int m = blockIdx.z;
    const short* A = g.A[m];
    const short* W = g.W[m];
    int lane = threadIdx.x & 63, wave = threadIdx.x >> 6;
    int lane15 = lane & 15, lhi = lane >> 4;
    int row0 = blockIdx.x * 128;
    const int K = HIDW;
    f32x4 acc[2][4] = {};
    for (int t = 0; t < 4; ++t) {
        int k0 = t * 64;
        STAGE_TILE(sA, A, K, row0, k0, 4)
        STAGE_TILE(sB, W, K, 0, k0, 2)
        __syncthreads();
        #pragma unroll
        for (int ks = 0; ks < 2; ++ks) {
            int kb = ks * 64 + lhi * 16;
            bf16x8 a[2], b[4];
            #pragma unroll
            for (int mi = 0; mi < 2; ++mi) a[mi] = ldfrag(sA, wave * 32 + mi * 16 + lane15, kb);
            #pragma unroll
            for (int ni = 0; ni < 4; ++ni) b[ni] = ldfrag(sB, ni * 16 + lane15, kb);
            #pragma unroll
            for (int mi = 0; mi < 2; ++mi)
                #pragma unroll
                for (int ni = 0; ni < 4; ++ni)
                    acc[mi][ni] = __builtin_amdgcn_mfma_f32_16x16x32_bf16(a[mi], b[ni], acc[mi][ni], 0, 0, 0);
        }
        __syncthreads();
    }
    const float* bias = g.bias[m];
    #pragma unroll
    for (int mi = 0; mi < 2; ++mi) {
        float v[4][4];
        float sumsq[4] = {};
        #pragma unroll
        for (int ni = 0; ni < 4; ++ni) {
            float bv = bias[ni * 16 + lane15];
            #pragma unroll
            for (int r = 0; r < 4; ++r) {
                float x = acc[mi][ni][r] + bv;
                v[ni][r] = x;
                sumsq[r] += x * x;
            }
        }
        #pragma unroll
        for (int r = 0; r < 4; ++r) {
            float s = sumsq[r];
            s += __shfl_xor(s, 1); s += __shfl_xor(s, 2);
            s += __shfl_xor(s, 4); s += __shfl_xor(s, 8);
            sumsq[r] = 1.f / fmaxf(sqrtf(s), 1e-12f);
        }
        int grow0 = row0 + wave * 32 + mi * 16 + lhi * 4;
        #pragma unroll
        for (int r = 0; r < 4; ++r) {
            int grow = grow0 + r;
            if (grow < NITEM) {
                float sc = sumsq[r];
                size_t o = (size_t)(NUSER + grow) * XW + m * DIMV;
                #pragma unroll
                for (int ni = 0; ni < 4; ++ni) {
                    float val = v[ni][r] * sc;
                    X[o + ni * 16 + lane15] = val;
                    Xb[o + ni * 16 + lane15] = f2bf(val);
                }
            }
        }
    }
}

// ================= user rows =================
__global__ void k_users_norm(const float* __restrict__ vp, const float* __restrict__ ap,
                             const float* __restrict__ tp, float* __restrict__ X,
                             short* __restrict__ Xb) {
    int gw = (blockIdx.x * blockDim.x + threadIdx.x) >> 6;
    int lane = threadIdx.x & 63;
    if (gw >= NUSER * 3) return;
    int u = gw / 3, m = gw % 3;
    const float* p = (m == 0) ? vp : (m == 1) ? ap : tp;
    float v = p[(size_t)u * DIMV + lane];
    float s = v * v;
    for (int o = 32; o > 0; o >>= 1) s += __shfl_xor(s, o);
    float sc = 1.f / fmaxf(sqrtf(s), 1e-12f);
    size_t o = (size_t)u * XW + m * DIMV + lane;
    float val = v * sc;
    X[o] = val;
    Xb[o] = f2bf(val);
}

// ================= gather SpMM, pipelined via readlane SGPR bases =================
// MODE 0: OUTB = bf16(A * INB)
// MODE 1: OUTf = Xf + INB_row + A * INB   (OUTf == Xf in-place safe)
template<int MODE>
__global__ __launch_bounds__(256)
void k_spmm(const int* __restrict__ rowptr, const int2* __restrict__ csr,
            const short* __restrict__ INB, const float* __restrict__ Xf,
            float* __restrict__ OUTf, short* __restrict__ OUTB) {
    int n = blockIdx.x * 4 + (threadIdx.x >> 6);
    int l = threadIdx.x & 63;
    if (n >= NN) return;
    int lo = rowptr[n], hi = rowptr[n + 1];
    int lc = l < 48 ? l : 47;              // clamp: lanes 48-63 duplicate, never stored
    float f0 = 0.f, f1 = 0.f, f2 = 0.f, f3 = 0.f;
    for (int base = lo; base < hi; base += 64) {
        int idx = base + l;
        int2 e = (idx < hi) ? csr[idx] : make_int2(0, 0);
        int m = hi - base; if (m > 64) m = 64;
        int j = 0;
        for (; j + 4 <= m; j += 4) {
            int s0 = __builtin_amdgcn_readlane(e.x, j + 0);
            int s1 = __builtin_amdgcn_readlane(e.x, j + 1);
            int s2 = __builtin_amdgcn_readlane(e.x, j + 2);
            int s3 = __builtin_amdgcn_readlane(e.x, j + 3);
            float w0 = __int_as_float(__builtin_amdgcn_readlane(e.y, j + 0));
            float w1 = __int_as_float(__builtin_amdgcn_readlane(e.y, j + 1));
            float w2 = __int_as_float(__builtin_amdgcn_readlane(e.y, j + 2));
            float w3 = __int_as_float(__builtin_amdgcn_readlane(e.y, j + 3));
            uint2 v0 = ((const uint2*)(INB + (size_t)s0 * XW))[lc];
            uint2 v1 = ((const uint2*)(INB + (size_t)s1 * XW))[lc];
            uint2 v2 = ((const uint2*)(INB + (size_t)s2 * XW))[lc];
            uint2 v3 = ((const uint2*)(INB + (size_t)s3 * XW))[lc];
            f0 += w0 * bflo(v0.x); f1 += w0 * bfhi(v0.x);
            f2 += w0 * bflo(v0.y); f3 += w0 * bfhi(v0.y);
            f0 += w1 * bflo(v1.x); f1 += w1 * bfhi(v1.x);
            f2 += w1 * bflo(v1.y); f3 += w1 * bfhi(v1.y);
            f0 += w2 * bflo(v2.x); f1 += w2 * bfhi(v2.x);
            f2 += w2 * bflo(v2.y); f3 += w2 * bfhi(v2.y);
            f0 += w3 * bflo(v3.x); f1 += w3 * bfhi(v3.x);
            f2 += w3 * bflo(v3.y); f3 += w3 * bfhi(v3.y);
        }
        for (; j < m; ++j) {
            int s0 = __builtin_amdgcn_readlane(e.x, j);
            float w0 = __int_as_float(__builtin_amdgcn_readlane(e.y, j));
            uint2 v0 = ((const uint2*)(INB + (size_t)s0 * XW))[lc];
            f0 += w0 * bflo(v0.x); f1 += w0 * bfhi(v0.x);
            f2 += w0 * bflo(v0.y); f3 += w0 * bfhi(v0.y);
        }
    }
    if (MODE == 1) {
        float4 xv = ((const float4*)(Xf + (size_t)n * XW))[lc];
        uint2 hb = ((const uint2*)(INB + (size_t)n * XW))[lc];
        f0 += xv.x + bflo(hb.x); f1 += xv.y + bfhi(hb.x);
        f2 += xv.z + bflo(hb.y); f3 += xv.w + bfhi(hb.y);
    }
    if (l < 48) {
        if (MODE == 0) {
            uint2 ob;
            ob.x = pack2(f0, f1);
            ob.y = pack2(f2, f3);
            ((uint2*)(OUTB + (size_t)n * XW))[l] = ob;
        } else {
            ((float4*)(OUTf + (size_t)n * XW))[l] = make_float4(f0, f1, f2, f3);
        }
    }
}

// ================= combine / usergraph / scores =================
__global__ void k_combine(const float* __restrict__ REP, const float* __restrict__ wu,
                          float* __restrict__ UR, float* __restrict__ RES) {
    int t = blockIdx.x * blockDim.x + threadIdx.x;
    if (t >= NN * DIMV) return;
    int n = t >> 6, d = t & 63;
    const float* r = REP + (size_t)n * XW;
    float r0 = r[d], r1 = r[DIMV + d], r2 = r[2 * DIMV + d];
    if (n < NUSER) {
        float w0 = wu[n * 3 + 0], w1 = wu[n * 3 + 1], w2 = wu[n * 3 + 2];
        UR[(size_t)n * DIMV + d] = r0 * w0 + r1 * w1 + r2 * w2;
    } else {
        RES[(size_t)n * DIMV + d] = (r0 + r1 + r2) * (1.f / 3.f);
    }
}
__global__ void k_usergraph(const float* __restrict__ UR, const int* __restrict__ g,
                            const float* __restrict__ w, float* __restrict__ RES) {
    int t = blockIdx.x * blockDim.x + threadIdx.x;
    if (t >= NUSER * DIMV) return;
    int n = t >> 6, d = t & 63;
    float acc = UR[(size_t)n * DIMV + d];
    for (int k = 0; k < KNB; ++k) {
        int nb = g[n * KNB + k];
        acc += w[n * KNB + k] * UR[(size_t)nb * DIMV + d];
    }
    RES[(size_t)n * DIMV + d] = acc;
}
__global__ void k_scores(const float* __restrict__ RES, const int* __restrict__ un,
                         const int* __restrict__ pn, const int* __restrict__ nn,
                         float* __restrict__ out) {
    int gw = (blockIdx.x * blockDim.x + threadIdx.x) >> 6;
    int lane = threadIdx.x & 63;
    if (gw >= NB) return;
    int u = un[gw], p = pn[gw], ng = nn[gw];
    float uv = RES[(size_t)u * DIMV + lane];
    float ps = uv * RES[(size_t)p * DIMV + lane];
    float ns = uv * RES[(size_t)ng * DIMV + lane];
    for (int o = 32; o > 0; o >>= 1) {
        ps += __shfl_xor(ps, o);
        ns += __shfl_xor(ns, o);
    }
    if (lane == 0) { out[gw] = ps; out[NB + gw] = ns; }
}

extern "C" void kernel_launch(void* const* d_in, const int* in_sizes, int n_in,
                              void* d_out, int out_size, void* d_ws, size_t ws_size,
                              hipStream_t stream) {
    const int*   un    = (const int*)d_in[0];
    const int*   pn    = (const int*)d_in[1];
    const int*   ngn   = (const int*)d_in[2];
    const int*   ug    = (const int*)d_in[3];
    const int*   eidx  = (const int*)d_in[4];
    const float* uwm   = (const float*)d_in[5];
    const float* feats[3] = { (const float*)d_in[6], (const float*)d_in[7], (const float*)d_in[8] };
    const float* prefs[3] = { (const float*)d_in[9], (const float*)d_in[10], (const float*)d_in[11] };
    const float* W1[3] = { (const float*)d_in[12], (const float*)d_in[16], (const float*)d_in[20] };
    const float* b1[3] = { (const float*)d_in[13], (const float*)d_in[17], (const float*)d_in[21] };
    const float* W2[3] = { (const float*)d_in[14], (const float*)d_in[18], (const float*)d_in[22] };
    const float* b2[3] = { (const float*)d_in[15], (const float*)d_in[19], (const float*)d_in[23] };
    const float* wu    = (const float*)d_in[24];
    float* out = (float*)d_out;

    const int* esrc = eidx;
    const int* edst = eidx + NE;

    // ---- workspace (phase-aliased) ----
    char* ws = (char*)d_ws;
    size_t off = 0;
    auto alloc = [&](size_t bytes) { void* p = ws + off; off = (off + bytes + 255) & ~(size_t)255; return p; };
    unsigned* deg    = (unsigned*)alloc(NN * 4);
    float*    dinv   = (float*)alloc(NN * 4);
    int*      rowptr = (int*)alloc((NN + 1) * 4);
    int*      bsum   = (int*)alloc(NCH * 4);
    int*      bscan  = (int*)alloc(NCH * 4);
    int2*     csr    = (int2*)alloc((size_t)NE * 8);
    // region1: Ab (77.0 MB) until gemm1; then X fp32 (46.08) + Xb bf16 (23.04)
    char* region1 = (char*)alloc((size_t)MPAD * 1280 * 2);
    short* Ab0 = (short*)region1;
    short* Ab1 = (short*)(region1 + (size_t)MPAD * 1024 * 2);
    short* Ab2 = (short*)(region1 + (size_t)MPAD * (1024 + 128) * 2);
    float* X   = (float*)region1;
    short* Xb  = (short*)(region1 + (size_t)NN * XW * 4);
    // region2: hidden (3x 30080x256 bf16 = 46.2 MB) until gemm2; then RES+UR+Hb
    char* region2 = (char*)alloc((size_t)3 * MPAD * HIDW * 2);
    short* hid[3] = { (short*)region2,
                      (short*)(region2 + (size_t)MPAD * HIDW * 2),
                      (short*)(region2 + (size_t)2 * MPAD * HIDW * 2) };
    float* RES = (float*)region2;
    float* UR  = (float*)(region2 + (size_t)NN * DIMV * 4 + 40960);
    short* Hb  = (short*)(region2 + (size_t)NN * DIMV * 4 + 40960 + (size_t)NUSER * DIMV * 4);
    short* w1b = (short*)alloc((size_t)256 * 1280 * 2);
    short* w1s[3] = { w1b, w1b + 256 * 1024, w1b + 256 * (1024 + 128) };
    short* w2b = (short*)alloc((size_t)3 * 64 * HIDW * 2);
    short* w2s[3] = { w2b, w2b + 64 * HIDW, w2b + 2 * 64 * HIDW };

    // ---- 1. convert fp32->bf16 ----
    CvtArgs ca;
    ca.src[0] = feats[0]; ca.src[1] = feats[1]; ca.src[2] = feats[2];
    ca.src[3] = W1[0];    ca.src[4] = W1[1];    ca.src[5] = W1[2];
    ca.src[6] = W2[0];    ca.src[7] = W2[1];    ca.src[8] = W2[2];
    ca.dst[0] = Ab0; ca.dst[1] = Ab1; ca.dst[2] = Ab2;
    ca.dst[3] = w1s[0]; ca.dst[4] = w1s[1]; ca.dst[5] = w1s[2];
    ca.dst[6] = w2s[0]; ca.dst[7] = w2s[1]; ca.dst[8] = w2s[2];
    k_convert<<<CVT_TOTAL / 256, 256, 0, stream>>>(ca);

    // ---- 2. CSR build ----
    hipMemsetAsync(deg, 0, NN * 4, stream);
    k_deg<<<(NE + 255) / 256, 256, 0, stream>>>(esrc, deg);
    k_dinv<<<(NN + 255) / 256, 256, 0, stream>>>(deg, dinv);
    k_bsum<<<NCH, 256, 0, stream>>>(deg, bsum);
    k_bscan<<<1, 256, 0, stream>>>(bsum, bscan);
    k_rowptr<<<NCH, 256, 0, stream>>>(deg, bscan, rowptr);
    hipMemsetAsync(deg, 0, NN * 4, stream);
    k_fill<<<(NE + 255) / 256, 256, 0, stream>>>(esrc, edst, dinv, rowptr, deg, csr);

    // ---- 3. gemm1 fused ----
    G1Args g1;
    for (int m = 0; m < 3; ++m) { g1.bias[m] = b1[m]; g1.C[m] = hid[m]; g1.W[m] = w1s[m]; }
    g1.A[0] = Ab0; g1.A[1] = Ab1; g1.A[2] = Ab2;
    g1.K[0] = 1024; g1.K[1] = 128; g1.K[2] = 128;
    gemm1_mfma<<<dim3(MPAD / 128, 2, 3), 256, 0, stream>>>(g1);

    // ---- 4. gemm2 fused ----
    G2Args g2;
    for (int m = 0; m < 3; ++m) { g2.A[m] = hid[m]; g2.W[m] = w2s[m]; g2.bias[m] = b2[m]; }
    gemm2_mfma<<<dim3(MPAD / 128, 1, 3), 256, 0, stream>>>(g2, X, Xb);
    k_users_norm<<<(NUSER * 3 * 64 + 255) / 256, 256, 0, stream>>>(prefs[0], prefs[1], prefs[2], X, Xb);

    // ---- 5. conv1: Hb = bf16(A * X) ----
    k_spmm<0><<<(NN + 3) / 4, 256, 0, stream>>>(rowptr, csr, Xb, nullptr, nullptr, Hb);

    // ---- 6. conv2: X(=REP) = X + Hb + A * Hb ----
    k_spmm<1><<<(NN + 3) / 4, 256, 0, stream>>>(rowptr, csr, Hb, X, X, nullptr);

    // ---- 7. combine / usergraph / scores ----
    k_combine<<<(NN * DIMV + 255) / 256, 256, 0, stream>>>(X, wu, UR, RES);
    k_usergraph<<<(NUSER * DIMV + 255) / 256, 256, 0, stream>>>(UR, ug, uwm, RES);
    k_scores<<<(NB * 64 + 255) / 256, 256, 0, stream>>>(RES, un, pn, ngn, out);
}

// Round 6
// 348.351 us; speedup vs baseline: 16.9969x; 1.0429x over previous
//
#include <hip/hip_runtime.h>
#include <hip/hip_bf16.h>
#include <math.h>

#define NUSER 30000
#define NITEM 30000
#define NN    60000
#define NE    1000000
#define DIMV  64
#define XW    192
#define HIDW  256
#define NB    2048
#define KNB   10
#define MPAD  30080
#define NCH   235      // ceil(NN/256)

typedef __attribute__((ext_vector_type(8))) short bf16x8;
typedef __attribute__((ext_vector_type(4))) float f32x4;

__device__ __forceinline__ short f2bf(float f) {
    union { float f; unsigned u; } v; v.f = f;
    unsigned r = v.u + 0x7fff + ((v.u >> 16) & 1);
    return (short)(r >> 16);
}
__device__ __forceinline__ float bflo(unsigned v) { return __int_as_float(v << 16); }
__device__ __forceinline__ float bfhi(unsigned v) { return __int_as_float(v & 0xffff0000u); }
__device__ __forceinline__ unsigned pack2(float a, float b) {
    return (unsigned)(unsigned short)f2bf(a) | ((unsigned)(unsigned short)f2bf(b) << 16);
}
__device__ __forceinline__ void async16(void* lds, const void* g) {
    __builtin_amdgcn_global_load_lds(
        (const __attribute__((address_space(1))) unsigned*)g,
        (__attribute__((address_space(3))) unsigned*)lds, 16, 0, 0);
}

// ================= degree / CSR =================
__global__ void k_deg(const int* __restrict__ src, unsigned* __restrict__ deg) {
    int e = blockIdx.x * blockDim.x + threadIdx.x;
    if (e < NE) atomicAdd(&deg[src[e]], 1u);
}
__global__ void k_dinv(const unsigned* __restrict__ deg, float* __restrict__ dinv) {
    int i = blockIdx.x * blockDim.x + threadIdx.x;
    if (i < NN) { unsigned d = deg[i]; dinv[i] = d ? rsqrtf((float)d) : 0.f; }
}
// ---- 3-stage block scan ----
__global__ __launch_bounds__(256)
void k_bsum(const unsigned* __restrict__ deg, int* __restrict__ bsum) {
    __shared__ int red[4];
    int g = blockIdx.x * 256 + threadIdx.x;
    int v = (g < NN) ? (int)deg[g] : 0;
    for (int o = 32; o > 0; o >>= 1) v += __shfl_down(v, o);
    int lane = threadIdx.x & 63, wave = threadIdx.x >> 6;
    if (lane == 0) red[wave] = v;
    __syncthreads();
    if (threadIdx.x == 0) bsum[blockIdx.x] = red[0] + red[1] + red[2] + red[3];
}
__global__ __launch_bounds__(256)
void k_bscan(const int* __restrict__ bsum, int* __restrict__ bscan) {
    __shared__ int s[256];
    int t = threadIdx.x;
    int v = (t < NCH) ? bsum[t] : 0;
    s[t] = v;
    __syncthreads();
    for (int o = 1; o < 256; o <<= 1) {
        int u = (t >= o) ? s[t - o] : 0;
        __syncthreads();
        s[t] += u;
        __syncthreads();
    }
    if (t < NCH) bscan[t] = s[t] - v;
}
__global__ __launch_bounds__(256)
void k_rowptr(const unsigned* __restrict__ deg, const int* __restrict__ bscan,
              int* __restrict__ rowptr) {
    __shared__ int s[256];
    int g = blockIdx.x * 256 + threadIdx.x, t = threadIdx.x;
    int v = (g < NN) ? (int)deg[g] : 0;
    s[t] = v;
    __syncthreads();
    for (int o = 1; o < 256; o <<= 1) {
        int u = (t >= o) ? s[t - o] : 0;
        __syncthreads();
        s[t] += u;
        __syncthreads();
    }
    int base = bscan[blockIdx.x];
    if (g < NN) rowptr[g] = base + s[t] - v;
    if (g == NN - 1) rowptr[NN] = base + s[t];
}
__global__ void k_fill(const int* __restrict__ src, const int* __restrict__ dst,
                       const float* __restrict__ dinv, const int* __restrict__ rowptr,
                       unsigned* __restrict__ cursor, int2* __restrict__ csr) {
    int e = blockIdx.x * blockDim.x + threadIdx.x;
    if (e >= NE) return;
    int s = src[e], d = dst[e];
    int pos = (int)atomicAdd(&cursor[d], 1u);
    int2 ew;
    ew.x = s;
    ew.y = __float_as_int(dinv[s] * dinv[d]);
    csr[rowptr[d] + pos] = ew;
}

// ================= fp32 -> bf16 convert, 8 cols/thread, shift indexing ==========
// chunk counts (8-col units, dst rows incl. pad): feats 30080*{1024,128,128}/8,
// W1 256*{1024,128,128}/8, W2 64*256/8 x3
struct CvtArgs { const float* src[9]; short* dst[9]; };
__constant__ __device__ const int C8PRE[10] = {0,3850240,4331520,4812800,4845568,
                                               4849664,4853760,4855808,4857856,4859904};
__constant__ __device__ const int C8SH[9]   = {7,4,4,7,4,4,5,5,5};   // log2(cpad/8)
__constant__ __device__ const int C8COLS[9] = {1024,128,100,1024,128,100,256,256,256};
__constant__ __device__ const int C8ROWS[9] = {30000,30000,30000,256,256,256,64,64,64};
#define CVT8_TOTAL 4859904

__global__ __launch_bounds__(256)
void k_convert(CvtArgs a) {
    int cid = blockIdx.x * 256 + threadIdx.x;
    if (cid >= CVT8_TOTAL) return;
    int j = 0;
    while (cid >= C8PRE[j + 1]) ++j;
    int local = cid - C8PRE[j];
    int sh = C8SH[j];
    int r = local >> sh;
    int col = (local & ((1 << sh) - 1)) * 8;
    int cols = C8COLS[j];
    bf16x8 o = (bf16x8)0;
    if (r < C8ROWS[j]) {
        const float* s = a.src[j] + (size_t)r * cols + col;
        if (col + 8 <= cols) {
            float4 f0 = *(const float4*)s;
            float4 f1 = *(const float4*)(s + 4);
            o[0] = f2bf(f0.x); o[1] = f2bf(f0.y); o[2] = f2bf(f0.z); o[3] = f2bf(f0.w);
            o[4] = f2bf(f1.x); o[5] = f2bf(f1.y); o[6] = f2bf(f1.z); o[7] = f2bf(f1.w);
        } else {
            #pragma unroll
            for (int q = 0; q < 8; ++q)
                if (col + q < cols) o[q] = f2bf(s[q]);
        }
    }
    *(bf16x8*)(a.dst[j] + ((size_t)r << (sh + 3)) + col) = o;
}

// ================= LDS helpers =================
__device__ __forceinline__ bf16x8 ldfrag(const short* lds, int row, int kbyte) {
    int off = (row * 128 + kbyte) ^ ((row & 7) << 4);
    return *(const bf16x8*)((const char*)lds + off);
}
#define STAGE_TILE(SMEM, BASEPTR, LDK, ROWOFF, K0, NITERS)                          \
    _Pragma("unroll")                                                                \
    for (int i_ = 0; i_ < (NITERS); ++i_) {                                          \
        int c_ = i_ * 256 + wave * 64 + lane;                                        \
        int r_ = c_ >> 3, slot_ = c_ & 7;                                            \
        int ss_ = slot_ ^ (r_ & 7);                                                  \
        const char* gp_ = (const char*)((BASEPTR) + (size_t)((ROWOFF) + r_) * (LDK)  \
                                        + (K0)) + ss_ * 16;                          \
        async16(&(SMEM)[(i_ * 256 + wave * 64) * 8], gp_);                           \
    }

// ================= GEMM1 fused =================
struct G1Args { const short* A[3]; const short* W[3]; const float* bias[3];
                short* C[3]; int K[3]; };
__global__ __launch_bounds__(256)
void gemm1_mfma(G1Args g) {
    __shared__ __align__(16) short sA[128 * 64];
    __shared__ __align__(16) short sB[128 * 64];
    int m = blockIdx.z;
    int K = g.K[m];
    const short* A = g.A[m];
    const short* W = g.W[m];
    int lane = threadIdx.x & 63, wave = threadIdx.x >> 6;
    int wr = wave >> 1, wc = wave & 1;
    int lane15 = lane & 15, lhi = lane >> 4;
    int row0 = blockIdx.x * 128, col0 = blockIdx.y * 128;
    f32x4 acc[4][4] = {};
    for (int t = 0; t < (K >> 6); ++t) {
        int k0 = t * 64;
        STAGE_TILE(sA, A, K, row0, k0, 4)
        STAGE_TILE(sB, W, K, col0, k0, 4)
        __syncthreads();
        #pragma unroll
        for (int ks = 0; ks < 2; ++ks) {
            int kb = ks * 64 + lhi * 16;
            bf16x8 a[4], b[4];
            #pragma unroll
            for (int mi = 0; mi < 4; ++mi) a[mi] = ldfrag(sA, wr * 64 + mi * 16 + lane15, kb);
            #pragma unroll
            for (int ni = 0; ni < 4; ++ni) b[ni] = ldfrag(sB, wc * 64 + ni * 16 + lane15, kb);
            #pragma unroll
            for (int mi = 0; mi < 4; ++mi)
                #pragma unroll
                for (int ni = 0; ni < 4; ++ni)
                    acc[mi][ni] = __builtin_amdgcn_mfma_f32_16x16x32_bf16(a[mi], b[ni], acc[mi][ni], 0, 0, 0);
        }
        __syncthreads();
    }
    short* C = g.C[m];
    const float* bias = g.bias[m];
    #pragma unroll
    for (int mi = 0; mi < 4; ++mi) {
        int grow0 = row0 + wr * 64 + mi * 16 + lhi * 4;
        #pragma unroll
        for (int ni = 0; ni < 4; ++ni) {
            int gcol = col0 + wc * 64 + ni * 16 + lane15;
            float bv = bias[gcol];
            #pragma unroll
            for (int r = 0; r < 4; ++r) {
                float v = acc[mi][ni][r] + bv;
                v = v > 0.f ? v : 0.01f * v;
                C[(size_t)(grow0 + r) * HIDW + gcol] = f2bf(v);
            }
        }
    }
}

// ================= GEMM2 fused + l2norm =================
struct G2Args { const short* A[3]; const short* W[3]; const float* bias[3]; };
__global__ __launch_bounds__(256)
void gemm2_mfma(G2Args g, float* __restrict__ X, short* __restrict__ Xb) {
    __shared__ __align__(16) short sA[128 * 64];
    __shared__ __align__(16) short sB[64 * 64];
    int m = blockIdx.z;
    const short* A = g.A[m];
    const short* W = g.W[m];
    int lane = threadIdx.x & 63, wave = threadIdx.x >> 6;
    int lane15 = lane & 15, lhi = lane >> 4;
    int row0 = blockIdx.x * 128;
    const int K = HIDW;
    f32x4 acc[2][4] = {};
    for (int t = 0; t < 4; ++t) {
        int k0 = t * 64;
        STAGE_TILE(sA, A, K, row0, k0, 4)
        STAGE_TILE(sB, W, K, 0, k0, 2)
        __syncthreads();
        #pragma unroll
        for (int ks = 0; ks < 2; ++ks) {
            int kb = ks * 64 + lhi * 16;
            bf16x8 a[2], b[4];
            #pragma unroll
            for (int mi = 0; mi < 2; ++mi) a[mi] = ldfrag(sA, wave * 32 + mi * 16 + lane15, kb);
            #pragma unroll
            for (int ni = 0; ni < 4; ++ni) b[ni] = ldfrag(sB, ni * 16 + lane15, kb);
            #pragma unroll
            for (int mi = 0; mi < 2; ++mi)
                #pragma unroll
                for (int ni = 0; ni < 4; ++ni)
                    acc[mi][ni] = __builtin_amdgcn_mfma_f32_16x16x32_bf16(a[mi], b[ni], acc[mi][ni], 0, 0, 0);
        }
        __syncthreads();
    }
    const float* bias = g.bias[m];
    #pragma unroll
    for (int mi = 0; mi < 2; ++mi) {
        float v[4][4];
        float sumsq[4] = {};
        #pragma unroll
        for (int ni = 0; ni < 4; ++ni) {
            float bv = bias[ni * 16 + lane15];
            #pragma unroll
            for (int r = 0; r < 4; ++r) {
                float x = acc[mi][ni][r] + bv;
                v[ni][r] = x;
                sumsq[r] += x * x;
            }
        }
        #pragma unroll
        for (int r = 0; r < 4; ++r) {
            float s = sumsq[r];
            s += __shfl_xor(s, 1); s += __shfl_xor(s, 2);
            s += __shfl_xor(s, 4); s += __shfl_xor(s, 8);
            sumsq[r] = 1.f / fmaxf(sqrtf(s), 1e-12f);
        }
        int grow0 = row0 + wave * 32 + mi * 16 + lhi * 4;
        #pragma unroll
        for (int r = 0; r < 4; ++r) {
            int grow = grow0 + r;
            if (grow < NITEM) {
                float sc = sumsq[r];
                size_t o = (size_t)(NUSER + grow) * XW + m * DIMV;
                #pragma unroll
                for (int ni = 0; ni < 4; ++ni) {
                    float val = v[ni][r] * sc;
                    X[o + ni * 16 + lane15] = val;
                    Xb[o + ni * 16 + lane15] = f2bf(val);
                }
            }
        }
    }
}

// ================= user rows =================
__global__ void k_users_norm(const float* __restrict__ vp, const float* __restrict__ ap,
                             const float* __restrict__ tp, float* __restrict__ X,
                             short* __restrict__ Xb) {
    int gw = (blockIdx.x * blockDim.x + threadIdx.x) >> 6;
    int lane = threadIdx.x & 63;
    if (gw >= NUSER * 3) return;
    int u = gw / 3, m = gw % 3;
    const float* p = (m == 0) ? vp : (m == 1) ? ap : tp;
    float v = p[(size_t)u * DIMV + lane];
    float s = v * v;
    for (int o = 32; o > 0; o >>= 1) s += __shfl_xor(s, o);
    float sc = 1.f / fmaxf(sqrtf(s), 1e-12f);
    size_t o = (size_t)u * XW + m * DIMV + lane;
    float val = v * sc;
    X[o] = val;
    Xb[o] = f2bf(val);
}

// ================= gather SpMM, readlane SGPR bases =================
template<int MODE>
__global__ __launch_bounds__(256)
void k_spmm(const int* __restrict__ rowptr, const int2* __restrict__ csr,
            const short* __restrict__ INB, const float* __restrict__ Xf,
            float* __restrict__ OUTf, short* __restrict__ OUTB) {
    int n = blockIdx.x * 4 + (threadIdx.x >> 6);
    int l = threadIdx.x & 63;
    if (n >= NN) return;
    int lo = rowptr[n], hi = rowptr[n + 1];
    int lc = l < 48 ? l : 47;
    float f0 = 0.f, f1 = 0.f, f2 = 0.f, f3 = 0.f;
    for (int base = lo; base < hi; base += 64) {
        int idx = base + l;
        int2 e = (idx < hi) ? csr[idx] : make_int2(0, 0);
        int m = hi - base; if (m > 64) m = 64;
        int j = 0;
        for (; j + 4 <= m; j += 4) {
            int s0 = __builtin_amdgcn_readlane(e.x, j + 0);
            int s1 = __builtin_amdgcn_readlane(e.x, j + 1);
            int s2 = __builtin_amdgcn_readlane(e.x, j + 2);
            int s3 = __builtin_amdgcn_readlane(e.x, j + 3);
            float w0 = __int_as_float(__builtin_amdgcn_readlane(e.y, j + 0));
            float w1 = __int_as_float(__builtin_amdgcn_readlane(e.y, j + 1));
            float w2 = __int_as_float(__builtin_amdgcn_readlane(e.y, j + 2));
            float w3 = __int_as_float(__builtin_amdgcn_readlane(e.y, j + 3));
            uint2 v0 = ((const uint2*)(INB + (size_t)s0 * XW))[lc];
            uint2 v1 = ((const uint2*)(INB + (size_t)s1 * XW))[lc];
            uint2 v2 = ((const uint2*)(INB + (size_t)s2 * XW))[lc];
            uint2 v3 = ((const uint2*)(INB + (size_t)s3 * XW))[lc];
            f0 += w0 * bflo(v0.x); f1 += w0 * bfhi(v0.x);
            f2 += w0 * bflo(v0.y); f3 += w0 * bfhi(v0.y);
            f0 += w1 * bflo(v1.x); f1 += w1 * bfhi(v1.x);
            f2 += w1 * bflo(v1.y); f3 += w1 * bfhi(v1.y);
            f0 += w2 * bflo(v2.x); f1 += w2 * bfhi(v2.x);
            f2 += w2 * bflo(v2.y); f3 += w2 * bfhi(v2.y);
            f0 += w3 * bflo(v3.x); f1 += w3 * bfhi(v3.x);
            f2 += w3 * bflo(v3.y); f3 += w3 * bfhi(v3.y);
        }
        for (; j < m; ++j) {
            int s0 = __builtin_amdgcn_readlane(e.x, j);
            float w0 = __int_as_float(__builtin_amdgcn_readlane(e.y, j));
            uint2 v0 = ((const uint2*)(INB + (size_t)s0 * XW))[lc];
            f0 += w0 * bflo(v0.x); f1 += w0 * bfhi(v0.x);
            f2 += w0 * bflo(v0.y); f3 += w0 * bfhi(v0.y);
        }
    }
    if (MODE == 1) {
        float4 xv = ((const float4*)(Xf + (size_t)n * XW))[lc];
        uint2 hb = ((const uint2*)(INB + (size_t)n * XW))[lc];
        f0 += xv.x + bflo(hb.x); f1 += xv.y + bfhi(hb.x);
        f2 += xv.z + bflo(hb.y); f3 += xv.w + bfhi(hb.y);
    }
    if (l < 48) {
        if (MODE == 0) {
            uint2 ob;
            ob.x = pack2(f0, f1);
            ob.y = pack2(f2, f3);
            ((uint2*)(OUTB + (size_t)n * XW))[l] = ob;
        } else {
            ((float4*)(OUTf + (size_t)n * XW))[l] = make_float4(f0, f1, f2, f3);
        }
    }
}

// ================= combine / usergraph / scores =================
__global__ void k_combine(const float* __restrict__ REP, const float* __restrict__ wu,
                          float* __restrict__ UR, float* __restrict__ RES) {
    int t = blockIdx.x * blockDim.x + threadIdx.x;
    if (t >= NN * DIMV) return;
    int n = t >> 6, d = t & 63;
    const float* r = REP + (size_t)n * XW;
    float r0 = r[d], r1 = r[DIMV + d], r2 = r[2 * DIMV + d];
    if (n < NUSER) {
        float w0 = wu[n * 3 + 0], w1 = wu[n * 3 + 1], w2 = wu[n * 3 + 2];
        UR[(size_t)n * DIMV + d] = r0 * w0 + r1 * w1 + r2 * w2;
    } else {
        RES[(size_t)n * DIMV + d] = (r0 + r1 + r2) * (1.f / 3.f);
    }
}
__global__ void k_usergraph(const float* __restrict__ UR, const int* __restrict__ g,
                            const float* __restrict__ w, float* __restrict__ RES) {
    int t = blockIdx.x * blockDim.x + threadIdx.x;
    if (t >= NUSER * DIMV) return;
    int n = t >> 6, d = t & 63;
    float acc = UR[(size_t)n * DIMV + d];
    for (int k = 0; k < KNB; ++k) {
        int nb = g[n * KNB + k];
        acc += w[n * KNB + k] * UR[(size_t)nb * DIMV + d];
    }
    RES[(size_t)n * DIMV + d] = acc;
}
__global__ void k_scores(const float* __restrict__ RES, const int* __restrict__ un,
                         const int* __restrict__ pn, const int* __restrict__ nn,
                         float* __restrict__ out) {
    int gw = (blockIdx.x * blockDim.x + threadIdx.x) >> 6;
    int lane = threadIdx.x & 63;
    if (gw >= NB) return;
    int u = un[gw], p = pn[gw], ng = nn[gw];
    float uv = RES[(size_t)u * DIMV + lane];
    float ps = uv * RES[(size_t)p * DIMV + lane];
    float ns = uv * RES[(size_t)ng * DIMV + lane];
    for (int o = 32; o > 0; o >>= 1) {
        ps += __shfl_xor(ps, o);
        ns += __shfl_xor(ns, o);
    }
    if (lane == 0) { out[gw] = ps; out[NB + gw] = ns; }
}

extern "C" void kernel_launch(void* const* d_in, const int* in_sizes, int n_in,
                              void* d_out, int out_size, void* d_ws, size_t ws_size,
                              hipStream_t stream) {
    const int*   un    = (const int*)d_in[0];
    const int*   pn    = (const int*)d_in[1];
    const int*   ngn   = (const int*)d_in[2];
    const int*   ug    = (const int*)d_in[3];
    const int*   eidx  = (const int*)d_in[4];
    const float* uwm   = (const float*)d_in[5];
    const float* feats[3] = { (const float*)d_in[6], (const float*)d_in[7], (const float*)d_in[8] };
    const float* prefs[3] = { (const float*)d_in[9], (const float*)d_in[10], (const float*)d_in[11] };
    const float* W1[3] = { (const float*)d_in[12], (const float*)d_in[16], (const float*)d_in[20] };
    const float* b1[3] = { (const float*)d_in[13], (const float*)d_in[17], (const float*)d_in[21] };
    const float* W2[3] = { (const float*)d_in[14], (const float*)d_in[18], (const float*)d_in[22] };
    const float* b2[3] = { (const float*)d_in[15], (const float*)d_in[19], (const float*)d_in[23] };
    const float* wu    = (const float*)d_in[24];
    float* out = (float*)d_out;

    const int* esrc = eidx;
    const int* edst = eidx + NE;

    // ---- workspace (phase-aliased) ----
    char* ws = (char*)d_ws;
    size_t off = 0;
    auto alloc = [&](size_t bytes) { void* p = ws + off; off = (off + bytes + 255) & ~(size_t)255; return p; };
    unsigned* deg    = (unsigned*)alloc(NN * 4);
    float*    dinv   = (float*)alloc(NN * 4);
    int*      rowptr = (int*)alloc((NN + 1) * 4);
    int*      bsum   = (int*)alloc(NCH * 4);
    int*      bscan  = (int*)alloc(NCH * 4);
    int2*     csr    = (int2*)alloc((size_t)NE * 8);
    char* region1 = (char*)alloc((size_t)MPAD * 1280 * 2);
    short* Ab0 = (short*)region1;
    short* Ab1 = (short*)(region1 + (size_t)MPAD * 1024 * 2);
    short* Ab2 = (short*)(region1 + (size_t)MPAD * (1024 + 128) * 2);
    float* X   = (float*)region1;
    short* Xb  = (short*)(region1 + (size_t)NN * XW * 4);
    char* region2 = (char*)alloc((size_t)3 * MPAD * HIDW * 2);
    short* hid[3] = { (short*)region2,
                      (short*)(region2 + (size_t)MPAD * HIDW * 2),
                      (short*)(region2 + (size_t)2 * MPAD * HIDW * 2) };
    float* RES = (float*)region2;
    float* UR  = (float*)(region2 + (size_t)NN * DIMV * 4 + 40960);
    short* Hb  = (short*)(region2 + (size_t)NN * DIMV * 4 + 40960 + (size_t)NUSER * DIMV * 4);
    short* w1b = (short*)alloc((size_t)256 * 1280 * 2);
    short* w1s[3] = { w1b, w1b + 256 * 1024, w1b + 256 * (1024 + 128) };
    short* w2b = (short*)alloc((size_t)3 * 64 * HIDW * 2);
    short* w2s[3] = { w2b, w2b + 64 * HIDW, w2b + 2 * 64 * HIDW };

    // ---- 1. convert fp32->bf16 ----
    CvtArgs ca;
    ca.src[0] = feats[0]; ca.src[1] = feats[1]; ca.src[2] = feats[2];
    ca.src[3] = W1[0];    ca.src[4] = W1[1];    ca.src[5] = W1[2];
    ca.src[6] = W2[0];    ca.src[7] = W2[1];    ca.src[8] = W2[2];
    ca.dst[0] = Ab0; ca.dst[1] = Ab1; ca.dst[2] = Ab2;
    ca.dst[3] = w1s[0]; ca.dst[4] = w1s[1]; ca.dst[5] = w1s[2];
    ca.dst[6] = w2s[0]; ca.dst[7] = w2s[1]; ca.dst[8] = w2s[2];
    k_convert<<<(CVT8_TOTAL + 255) / 256, 256, 0, stream>>>(ca);

    // ---- 2. CSR build ----
    hipMemsetAsync(deg, 0, NN * 4, stream);
    k_deg<<<(NE + 255) / 256, 256, 0, stream>>>(esrc, deg);
    k_dinv<<<(NN + 255) / 256, 256, 0, stream>>>(deg, dinv);
    k_bsum<<<NCH, 256, 0, stream>>>(deg, bsum);
    k_bscan<<<1, 256, 0, stream>>>(bsum, bscan);
    k_rowptr<<<NCH, 256, 0, stream>>>(deg, bscan, rowptr);
    hipMemsetAsync(deg, 0, NN * 4, stream);
    k_fill<<<(NE + 255) / 256, 256, 0, stream>>>(esrc, edst, dinv, rowptr, deg, csr);

    // ---- 3. gemm1 fused ----
    G1Args g1;
    for (int m = 0; m < 3; ++m) { g1.bias[m] = b1[m]; g1.C[m] = hid[m]; g1.W[m] = w1s[m]; }
    g1.A[0] = Ab0; g1.A[1] = Ab1; g1.A[2] = Ab2;
    g1.K[0] = 1024; g1.K[1] = 128; g1.K[2] = 128;
    gemm1_mfma<<<dim3(MPAD / 128, 2, 3), 256, 0, stream>>>(g1);

    // ---- 4. gemm2 fused ----
    G2Args g2;
    for (int m = 0; m < 3; ++m) { g2.A[m] = hid[m]; g2.W[m] = w2s[m]; g2.bias[m] = b2[m]; }
    gemm2_mfma<<<dim3(MPAD / 128, 1, 3), 256, 0, stream>>>(g2, X, Xb);
    k_users_norm<<<(NUSER * 3 * 64 + 255) / 256, 256, 0, stream>>>(prefs[0], prefs[1], prefs[2], X, Xb);

    // ---- 5. conv1: Hb = bf16(A * X) ----
    k_spmm<0><<<(NN + 3) / 4, 256, 0, stream>>>(rowptr, csr, Xb, nullptr, nullptr, Hb);

    // ---- 6. conv2: X(=REP) = X + Hb + A * Hb ----
    k_spmm<1><<<(NN + 3) / 4, 256, 0, stream>>>(rowptr, csr, Hb, X, X, nullptr);

    // ---- 7. combine / usergraph / scores ----
    k_combine<<<(NN * DIMV + 255) / 256, 256, 0, stream>>>(X, wu, UR, RES);
    k_usergraph<<<(NUSER * DIMV + 255) / 256, 256, 0, stream>>>(UR, ug, uwm, RES);
    k_scores<<<(NB * 64 + 255) / 256, 256, 0, stream>>>(RES, un, pn, ngn, out);
}